// Round 4
// baseline (1774.186 us; speedup 1.0000x reference)
//
#include <hip/hip_runtime.h>
#include <math.h>

#define NN 100000
#define NE 1600000
#define BSZ 64                          // dst nodes per bucket
#define NBUCK ((NN + BSZ - 1) / BSZ)    // 1563

// ---------------------------------------------------------------------------
// Degree histogram (int atomics over 100k counters — low contention).
// ---------------------------------------------------------------------------
__global__ __launch_bounds__(256) void hist_kernel(
    const int* __restrict__ dst, int* __restrict__ deg) {
  int e = blockIdx.x * 256 + threadIdx.x;
  if (e >= NE) return;
  atomicAdd(&deg[dst[e]], 1);
}

// ---------------------------------------------------------------------------
// Bucket counts = sum of deg over each 64-node bucket (one wave per bucket).
// ---------------------------------------------------------------------------
__global__ __launch_bounds__(256) void bsum64_kernel(
    const int* __restrict__ deg, int* __restrict__ bcnt) {
  int b = blockIdx.x * 4 + (threadIdx.x >> 6);
  if (b >= NBUCK) return;
  int lane = threadIdx.x & 63;
  int i = b * BSZ + lane;
  int v = (i < NN) ? deg[i] : 0;
#pragma unroll
  for (int d = 1; d < 64; d <<= 1) v += __shfl_xor(v, d);
  if (lane == 0) bcnt[b] = v;
}

// ---------------------------------------------------------------------------
// Exclusive scan of 1563 bucket counts (single block, 2 chunks + carry).
// ---------------------------------------------------------------------------
__global__ __launch_bounds__(1024) void bscan_kernel(
    const int* __restrict__ bcnt, int* __restrict__ boff,
    int* __restrict__ bcur) {
  __shared__ int buf[2][1024];
  __shared__ int carry_s;
  int tid = threadIdx.x;
  if (tid == 0) carry_s = 0;
  __syncthreads();
  for (int base = 0; base < NBUCK; base += 1024) {
    int i = base + tid;
    int v = (i < NBUCK) ? bcnt[i] : 0;
    buf[0][tid] = v;
    __syncthreads();
    int pp = 0;
    for (int d = 1; d < 1024; d <<= 1) {
      buf[pp ^ 1][tid] = buf[pp][tid] + ((tid >= d) ? buf[pp][tid - d] : 0);
      pp ^= 1;
      __syncthreads();
    }
    int incl = buf[pp][tid];
    int carry = carry_s;
    __syncthreads();
    if (i < NBUCK) {
      int e = carry + incl - v;
      boff[i] = e;
      bcur[i] = e;
    }
    if (tid == 1023) carry_s = carry + incl;
    __syncthreads();
  }
  if (tid == 0) boff[NBUCK] = NE;
}

// ---------------------------------------------------------------------------
// Scatter edges into bucket-ordered ebuf, packed (dst&63)<<17 | src.
// Writes confined to ~4 KB live region per bucket -> L2-resident, ~no
// write amplification (vs 16x for the per-node perm scatter).
// ---------------------------------------------------------------------------
__global__ __launch_bounds__(256) void scatter2_kernel(
    const int* __restrict__ src, const int* __restrict__ dst,
    int* __restrict__ bcur, unsigned int* __restrict__ ebuf) {
  int e = blockIdx.x * 256 + threadIdx.x;
  if (e >= NE) return;
  int d = dst[e];
  int p = atomicAdd(&bcur[d >> 6], 1);
  ebuf[p] = ((unsigned int)(d & 63) << 17) | (unsigned int)src[e];
}

// ---------------------------------------------------------------------------
// Fused layer-1 mean aggregation: one block per bucket.
// 32 KB LDS accumulator acc[64][128]; waves gather full x rows and
// ds_add_f32 into the dst-local row (lane / lane+64 -> conflict-free).
// ---------------------------------------------------------------------------
__global__ __launch_bounds__(256) void mean1_fused_kernel(
    const float* __restrict__ x, const unsigned int* __restrict__ ebuf,
    const int* __restrict__ boff, const int* __restrict__ deg,
    float* __restrict__ mean1) {
  __shared__ float acc[BSZ][128];
  int tid = threadIdx.x;
  int b = blockIdx.x;
  float* af = &acc[0][0];
  for (int i = tid; i < BSZ * 128; i += 256) af[i] = 0.0f;
  __syncthreads();

  int e0 = boff[b], e1 = boff[b + 1];
  int lane = tid & 63, w = tid >> 6;
  int e = e0 + w;
  for (; e + 4 < e1; e += 8) {   // unroll-2 (stride 4 per wave)
    unsigned int p0 = ebuf[e], p1 = ebuf[e + 4];
    int s0 = p0 & 0x1FFFF, d0 = p0 >> 17;
    int s1 = p1 & 0x1FFFF, d1 = p1 >> 17;
    float a0 = x[(size_t)s0 * 128 + lane];
    float b0 = x[(size_t)s0 * 128 + 64 + lane];
    float a1 = x[(size_t)s1 * 128 + lane];
    float b1v = x[(size_t)s1 * 128 + 64 + lane];
    atomicAdd(&acc[d0][lane], a0);
    atomicAdd(&acc[d0][64 + lane], b0);
    atomicAdd(&acc[d1][lane], a1);
    atomicAdd(&acc[d1][64 + lane], b1v);
  }
  if (e < e1) {
    unsigned int p0 = ebuf[e];
    int s0 = p0 & 0x1FFFF, d0 = p0 >> 17;
    atomicAdd(&acc[d0][lane], x[(size_t)s0 * 128 + lane]);
    atomicAdd(&acc[d0][64 + lane], x[(size_t)s0 * 128 + 64 + lane]);
  }
  __syncthreads();

  int node0 = b * BSZ;
  for (int r = w; r < BSZ; r += 4) {
    int node = node0 + r;
    if (node >= NN) break;
    float rd = 1.0f / fmaxf((float)deg[node], 1.0f);
    mean1[(size_t)node * 128 + lane] = acc[r][lane] * rd;
    mean1[(size_t)node * 128 + 64 + lane] = acc[r][64 + lane] * rd;
  }
}

// ---------------------------------------------------------------------------
// GEMM1: h = relu([x | mean1] @ [ws1; wn1] + b1)
// M=NN, K=256, N=128. BM=128, BN=128, BK=16, 256 threads, 8x8/thread.
// h aliases mean1 — each block reads only its own 128 rows before writing.
// ---------------------------------------------------------------------------
__global__ __launch_bounds__(256) void gemm1_kernel(
    const float* __restrict__ x, const float* __restrict__ hn,
    const float* __restrict__ ws1, const float* __restrict__ wn1,
    const float* __restrict__ b1, float* __restrict__ h) {
  __shared__ float As[16][132];
  __shared__ float Bs[16][128];

  int tid = threadIdx.x;
  int tn = tid & 15;
  int tm = tid >> 4;
  int row0 = blockIdx.x * 128;

  float acc[8][8];
#pragma unroll
  for (int i = 0; i < 8; i++)
#pragma unroll
    for (int j = 0; j < 8; j++) acc[i][j] = 0.0f;

  for (int k0 = 0; k0 < 256; k0 += 16) {
    bool neigh = (k0 >= 128);
    int kk0 = neigh ? (k0 - 128) : k0;
    const float* Asrc = neigh ? hn : x;
    const float* Bsrc = (neigh ? wn1 : ws1) + (size_t)kk0 * 128;

#pragma unroll
    for (int i = 0; i < 2; i++) {
      int flat = tid * 4 + i * 1024;
      int r = flat >> 4;
      int kk = flat & 15;
      int row = row0 + r;
      if (row >= NN) row = NN - 1;
      float4 v = *(const float4*)(Asrc + (size_t)row * 128 + kk0 + kk);
      As[kk][r] = v.x; As[kk + 1][r] = v.y;
      As[kk + 2][r] = v.z; As[kk + 3][r] = v.w;
    }
    {
      int r = tid >> 4;
      int n = (tid & 15) * 8;
      const float* p = Bsrc + r * 128 + n;
      *(float4*)&Bs[r][n] = *(const float4*)(p);
      *(float4*)&Bs[r][n + 4] = *(const float4*)(p + 4);
    }
    __syncthreads();

#pragma unroll
    for (int k = 0; k < 16; k++) {
      float a[8], b[8];
      *(float4*)&a[0] = *(const float4*)&As[k][tm * 8];
      *(float4*)&a[4] = *(const float4*)&As[k][tm * 8 + 4];
      *(float4*)&b[0] = *(const float4*)&Bs[k][tn * 8];
      *(float4*)&b[4] = *(const float4*)&Bs[k][tn * 8 + 4];
#pragma unroll
      for (int i = 0; i < 8; i++)
#pragma unroll
        for (int j = 0; j < 8; j++) acc[i][j] += a[i] * b[j];
    }
    __syncthreads();
  }

#pragma unroll
  for (int i = 0; i < 8; i++) {
    int row = row0 + tm * 8 + i;
    if (row < NN) {
#pragma unroll
      for (int j = 0; j < 8; j += 4) {
        int col = tn * 8 + j;
        float4 v;
        v.x = fmaxf(acc[i][j + 0] + b1[col + 0], 0.0f);
        v.y = fmaxf(acc[i][j + 1] + b1[col + 1], 0.0f);
        v.z = fmaxf(acc[i][j + 2] + b1[col + 2], 0.0f);
        v.w = fmaxf(acc[i][j + 3] + b1[col + 3], 0.0f);
        *(float4*)(h + (size_t)row * 128 + col) = v;
      }
    }
  }
}

// ---------------------------------------------------------------------------
// GEMM2: [oself | h2] = h @ [ws2 | wn2]   (M=NN, K=128, N=32)
// ---------------------------------------------------------------------------
__global__ __launch_bounds__(256) void gemm2_kernel(
    const float* __restrict__ h, const float* __restrict__ ws2,
    const float* __restrict__ wn2, float* __restrict__ oself,
    float* __restrict__ h2) {
  __shared__ float As[16][132];
  __shared__ float Bs[16][32];

  int tid = threadIdx.x;
  int tn = tid & 15;
  int tm = tid >> 4;
  int row0 = blockIdx.x * 128;

  float acc[8][2];
#pragma unroll
  for (int i = 0; i < 8; i++) { acc[i][0] = 0.0f; acc[i][1] = 0.0f; }

  for (int k0 = 0; k0 < 128; k0 += 16) {
#pragma unroll
    for (int i = 0; i < 2; i++) {
      int flat = tid * 4 + i * 1024;
      int r = flat >> 4;
      int kk = flat & 15;
      int row = row0 + r;
      if (row >= NN) row = NN - 1;
      float4 v = *(const float4*)(h + (size_t)row * 128 + k0 + kk);
      As[kk][r] = v.x; As[kk + 1][r] = v.y;
      As[kk + 2][r] = v.z; As[kk + 3][r] = v.w;
    }
    {
      int flat = tid * 2;
      int r = flat >> 5;
      int c = flat & 31;
      int k = k0 + r;
      float2 v;
      if (c < 16) {
        v = *(const float2*)(ws2 + (size_t)k * 16 + c);
      } else {
        v = *(const float2*)(wn2 + (size_t)k * 16 + (c - 16));
      }
      *(float2*)&Bs[r][c] = v;
    }
    __syncthreads();

#pragma unroll
    for (int k = 0; k < 16; k++) {
      float a[8];
      *(float4*)&a[0] = *(const float4*)&As[k][tm * 8];
      *(float4*)&a[4] = *(const float4*)&As[k][tm * 8 + 4];
      float2 bv = *(const float2*)&Bs[k][tn * 2];
#pragma unroll
      for (int i = 0; i < 8; i++) {
        acc[i][0] += a[i] * bv.x;
        acc[i][1] += a[i] * bv.y;
      }
    }
    __syncthreads();
  }

#pragma unroll
  for (int i = 0; i < 8; i++) {
    int row = row0 + tm * 8 + i;
    if (row < NN) {
      int col = tn * 2;
      float2 v; v.x = acc[i][0]; v.y = acc[i][1];
      if (col < 16) {
        *(float2*)(oself + (size_t)row * 16 + col) = v;
      } else {
        *(float2*)(h2 + (size_t)row * 16 + (col - 16)) = v;
      }
    }
  }
}

// ---------------------------------------------------------------------------
// Fused layer-2 mean aggregation: one block per bucket, 4 KB LDS acc[64][16].
// 16 lanes per edge.
// ---------------------------------------------------------------------------
__global__ __launch_bounds__(256) void mean2_fused_kernel(
    const float* __restrict__ h2, const unsigned int* __restrict__ ebuf,
    const int* __restrict__ boff, const int* __restrict__ deg,
    float* __restrict__ mean2) {
  __shared__ float acc[BSZ][16];
  int tid = threadIdx.x;
  int b = blockIdx.x;
  float* af = &acc[0][0];
  for (int i = tid; i < BSZ * 16; i += 256) af[i] = 0.0f;
  __syncthreads();

  int e0 = boff[b], e1 = boff[b + 1];
  int c = tid & 15;
  int g = tid >> 4;   // 16 edge-groups
  for (int e = e0 + g; e < e1; e += 16) {
    unsigned int pk = ebuf[e];
    int s = pk & 0x1FFFF, dl = pk >> 17;
    float v = h2[(size_t)s * 16 + c];
    atomicAdd(&acc[dl][c], v);
  }
  __syncthreads();

  int node0 = b * BSZ;
  for (int i = tid; i < BSZ * 16; i += 256) {
    int r = i >> 4;
    int node = node0 + r;
    if (node < NN) {
      float rd = 1.0f / fmaxf((float)deg[node], 1.0f);
      mean2[(size_t)node * 16 + (i & 15)] = acc[r][i & 15] * rd;
    }
  }
}

// ---------------------------------------------------------------------------
// Final: logits = oself + b2 + mean2; out = log_softmax(logits).
// ---------------------------------------------------------------------------
__global__ __launch_bounds__(256) void final_kernel(
    const float* __restrict__ oself, const float* __restrict__ mean2,
    const float* __restrict__ b2, float* __restrict__ out) {
  int i = blockIdx.x * 256 + threadIdx.x;
  if (i >= NN) return;
  float l[16];
  const float4* po = (const float4*)(oself + (size_t)i * 16);
  const float4* pa = (const float4*)(mean2 + (size_t)i * 16);
#pragma unroll
  for (int q = 0; q < 4; q++) {
    float4 o = po[q], a = pa[q];
    l[q * 4 + 0] = o.x + b2[q * 4 + 0] + a.x;
    l[q * 4 + 1] = o.y + b2[q * 4 + 1] + a.y;
    l[q * 4 + 2] = o.z + b2[q * 4 + 2] + a.z;
    l[q * 4 + 3] = o.w + b2[q * 4 + 3] + a.w;
  }
  float m = l[0];
#pragma unroll
  for (int c = 1; c < 16; c++) m = fmaxf(m, l[c]);
  float s = 0.0f;
#pragma unroll
  for (int c = 0; c < 16; c++) s += expf(l[c] - m);
  float ls = logf(s);
  float4* po2 = (float4*)(out + (size_t)i * 16);
#pragma unroll
  for (int q = 0; q < 4; q++) {
    float4 v;
    v.x = l[q * 4 + 0] - m - ls;
    v.y = l[q * 4 + 1] - m - ls;
    v.z = l[q * 4 + 2] - m - ls;
    v.w = l[q * 4 + 3] - m - ls;
    po2[q] = v;
  }
}

// ---------------------------------------------------------------------------
extern "C" void kernel_launch(void* const* d_in, const int* in_sizes, int n_in,
                              void* d_out, int out_size, void* d_ws, size_t ws_size,
                              hipStream_t stream) {
  const float* x   = (const float*)d_in[0];
  const int*   src = (const int*)d_in[1];
  const int*   dst = (const int*)d_in[2];
  const float* ws1 = (const float*)d_in[3];
  const float* wn1 = (const float*)d_in[4];
  const float* b1  = (const float*)d_in[5];
  const float* ws2 = (const float*)d_in[6];
  const float* wn2 = (const float*)d_in[7];
  const float* b2  = (const float*)d_in[8];
  float* out = (float*)d_out;

  // workspace layout
  char* p = (char*)d_ws;
  int* deg  = (int*)p;  p += (size_t)NN * 4;
  int* bcnt = (int*)p;  p += (size_t)((NBUCK + 31) & ~31) * 4;
  int* boff = (int*)p;  p += (size_t)((NBUCK + 32) & ~31) * 4;  // NBUCK+1 used
  int* bcur = (int*)p;  p += (size_t)((NBUCK + 31) & ~31) * 4;
  unsigned int* ebuf = (unsigned int*)p; p += (size_t)NE * 4;
  float* mean1 = (float*)p; p += (size_t)NN * 128 * 4;
  float* h     = mean1;  // alias: gemm1 reads its rows before writing them
  float* h2    = (float*)p; p += (size_t)NN * 16 * 4;
  float* osf   = (float*)p; p += (size_t)NN * 16 * 4;
  float* mean2 = (float*)p; p += (size_t)NN * 16 * 4;

  hipMemsetAsync(deg, 0, (size_t)NN * 4, stream);

  hist_kernel<<<(NE + 255) / 256, 256, 0, stream>>>(dst, deg);
  bsum64_kernel<<<(NBUCK + 3) / 4, 256, 0, stream>>>(deg, bcnt);
  bscan_kernel<<<1, 1024, 0, stream>>>(bcnt, boff, bcur);
  scatter2_kernel<<<(NE + 255) / 256, 256, 0, stream>>>(src, dst, bcur, ebuf);
  mean1_fused_kernel<<<NBUCK, 256, 0, stream>>>(x, ebuf, boff, deg, mean1);
  gemm1_kernel<<<(NN + 127) / 128, 256, 0, stream>>>(x, mean1, ws1, wn1, b1, h);
  gemm2_kernel<<<(NN + 127) / 128, 256, 0, stream>>>(h, ws2, wn2, osf, h2);
  mean2_fused_kernel<<<NBUCK, 256, 0, stream>>>(h2, ebuf, boff, deg, mean2);
  final_kernel<<<(NN + 255) / 256, 256, 0, stream>>>(osf, mean2, b2, out);
}

// Round 5
// 621.969 us; speedup vs baseline: 2.8525x; 2.8525x over previous
//
#include <hip/hip_runtime.h>
#include <math.h>

#define NN 100000
#define NE 1600000
#define BSZ 64                          // dst nodes per bucket
#define NBUCK ((NN + BSZ - 1) / BSZ)    // 1563

// ---------------------------------------------------------------------------
// Degree histogram (int atomics over 100k counters — low contention).
// ---------------------------------------------------------------------------
__global__ __launch_bounds__(256) void hist_kernel(
    const int* __restrict__ dst, int* __restrict__ deg) {
  int e = blockIdx.x * 256 + threadIdx.x;
  if (e >= NE) return;
  atomicAdd(&deg[dst[e]], 1);
}

// ---------------------------------------------------------------------------
// Bucket counts = sum of deg over each 64-node bucket (one wave per bucket).
// ---------------------------------------------------------------------------
__global__ __launch_bounds__(256) void bsum64_kernel(
    const int* __restrict__ deg, int* __restrict__ bcnt) {
  int b = blockIdx.x * 4 + (threadIdx.x >> 6);
  if (b >= NBUCK) return;
  int lane = threadIdx.x & 63;
  int i = b * BSZ + lane;
  int v = (i < NN) ? deg[i] : 0;
#pragma unroll
  for (int d = 1; d < 64; d <<= 1) v += __shfl_xor(v, d);
  if (lane == 0) bcnt[b] = v;
}

// ---------------------------------------------------------------------------
// Exclusive scan of 1563 bucket counts (single block, 2 chunks + carry).
// ---------------------------------------------------------------------------
__global__ __launch_bounds__(1024) void bscan_kernel(
    const int* __restrict__ bcnt, int* __restrict__ boff,
    int* __restrict__ bcur) {
  __shared__ int buf[2][1024];
  __shared__ int carry_s;
  int tid = threadIdx.x;
  if (tid == 0) carry_s = 0;
  __syncthreads();
  for (int base = 0; base < NBUCK; base += 1024) {
    int i = base + tid;
    int v = (i < NBUCK) ? bcnt[i] : 0;
    buf[0][tid] = v;
    __syncthreads();
    int pp = 0;
    for (int d = 1; d < 1024; d <<= 1) {
      buf[pp ^ 1][tid] = buf[pp][tid] + ((tid >= d) ? buf[pp][tid - d] : 0);
      pp ^= 1;
      __syncthreads();
    }
    int incl = buf[pp][tid];
    int carry = carry_s;
    __syncthreads();
    if (i < NBUCK) {
      int e = carry + incl - v;
      boff[i] = e;
      bcur[i] = e;
    }
    if (tid == 1023) carry_s = carry + incl;
    __syncthreads();
  }
  if (tid == 0) boff[NBUCK] = NE;
}

// ---------------------------------------------------------------------------
// Scatter edges into bucket-ordered ebuf, packed (dst&63)<<17 | src.
// Writes confined to ~4 KB live region per bucket -> L2-resident.
// ---------------------------------------------------------------------------
__global__ __launch_bounds__(256) void scatter2_kernel(
    const int* __restrict__ src, const int* __restrict__ dst,
    int* __restrict__ bcur, unsigned int* __restrict__ ebuf) {
  int e = blockIdx.x * 256 + threadIdx.x;
  if (e >= NE) return;
  int d = dst[e];
  int p = atomicAdd(&bcur[d >> 6], 1);
  ebuf[p] = ((unsigned int)(d & 63) << 17) | (unsigned int)src[e];
}

// ---------------------------------------------------------------------------
// Per-bucket counting sort: bucket-ordered ebuf -> per-node CSR perm,
// and per-node off. One block per bucket; 1 LDS int atomic per edge;
// perm writes land inside the bucket's own [e0,e1) range (L2-resident).
// ---------------------------------------------------------------------------
__global__ __launch_bounds__(256) void bucket_sort_kernel(
    const unsigned int* __restrict__ ebuf, const int* __restrict__ boff,
    const int* __restrict__ deg, int* __restrict__ off,
    int* __restrict__ perm) {
  __shared__ int loc_off[BSZ];
  __shared__ int cnt[BSZ];
  int tid = threadIdx.x;
  int b = blockIdx.x;
  int e0 = boff[b], e1 = boff[b + 1];

  if (tid < BSZ) {
    int node = b * BSZ + tid;
    int v = (node < NN) ? deg[node] : 0;
    // wave-wide inclusive scan (threads 0..63 are one wave)
    int incl = v;
#pragma unroll
    for (int d = 1; d < 64; d <<= 1) {
      int t = __shfl_up(incl, d);
      if (tid >= d) incl += t;
    }
    int excl = incl - v;
    loc_off[tid] = e0 + excl;
    cnt[tid] = 0;
    if (node < NN) off[node] = e0 + excl;
  }
  __syncthreads();

  for (int e = e0 + tid; e < e1; e += 256) {
    unsigned int pk = ebuf[e];
    int dl = pk >> 17;
    int p = loc_off[dl] + atomicAdd(&cnt[dl], 1);
    perm[p] = (int)(pk & 0x1FFFF);
  }
}

// ---------------------------------------------------------------------------
// Layer-1 mean aggregation, gather form: one wave per node, 2 floats/lane,
// register accumulate (no atomics).
// ---------------------------------------------------------------------------
__global__ __launch_bounds__(256) void mean1_kernel(
    const float* __restrict__ x, const int* __restrict__ off,
    const int* __restrict__ deg, const int* __restrict__ perm,
    float* __restrict__ mean1) {
  int node = blockIdx.x * 4 + (threadIdx.x >> 6);
  int lane = threadIdx.x & 63;
  if (node >= NN) return;
  int o = off[node], dg = deg[node];
  float accx = 0.f, accy = 0.f;
  int j = 0;
  for (; j + 2 <= dg; j += 2) {
    int s0 = perm[o + j], s1 = perm[o + j + 1];
    float2 v0 = *(const float2*)(x + (size_t)s0 * 128 + lane * 2);
    float2 v1 = *(const float2*)(x + (size_t)s1 * 128 + lane * 2);
    accx += v0.x + v1.x;
    accy += v0.y + v1.y;
  }
  if (j < dg) {
    int s0 = perm[o + j];
    float2 v0 = *(const float2*)(x + (size_t)s0 * 128 + lane * 2);
    accx += v0.x;
    accy += v0.y;
  }
  float rd = 1.0f / fmaxf((float)dg, 1.0f);
  float2 r;
  r.x = accx * rd;
  r.y = accy * rd;
  *(float2*)(mean1 + (size_t)node * 128 + lane * 2) = r;
}

// ---------------------------------------------------------------------------
// GEMM1: h = relu([x | mean1] @ [ws1; wn1] + b1)
// M=NN, K=256, N=128. BM=128, BN=128, BK=16, 256 threads, 8x8/thread.
// h aliases mean1 — each block reads only its own 128 rows before writing.
// ---------------------------------------------------------------------------
__global__ __launch_bounds__(256) void gemm1_kernel(
    const float* __restrict__ x, const float* __restrict__ hn,
    const float* __restrict__ ws1, const float* __restrict__ wn1,
    const float* __restrict__ b1, float* __restrict__ h) {
  __shared__ float As[16][132];
  __shared__ float Bs[16][128];

  int tid = threadIdx.x;
  int tn = tid & 15;
  int tm = tid >> 4;
  int row0 = blockIdx.x * 128;

  float acc[8][8];
#pragma unroll
  for (int i = 0; i < 8; i++)
#pragma unroll
    for (int j = 0; j < 8; j++) acc[i][j] = 0.0f;

  for (int k0 = 0; k0 < 256; k0 += 16) {
    bool neigh = (k0 >= 128);
    int kk0 = neigh ? (k0 - 128) : k0;
    const float* Asrc = neigh ? hn : x;
    const float* Bsrc = (neigh ? wn1 : ws1) + (size_t)kk0 * 128;

#pragma unroll
    for (int i = 0; i < 2; i++) {
      int flat = tid * 4 + i * 1024;
      int r = flat >> 4;
      int kk = flat & 15;
      int row = row0 + r;
      if (row >= NN) row = NN - 1;
      float4 v = *(const float4*)(Asrc + (size_t)row * 128 + kk0 + kk);
      As[kk][r] = v.x; As[kk + 1][r] = v.y;
      As[kk + 2][r] = v.z; As[kk + 3][r] = v.w;
    }
    {
      int r = tid >> 4;
      int n = (tid & 15) * 8;
      const float* p = Bsrc + r * 128 + n;
      *(float4*)&Bs[r][n] = *(const float4*)(p);
      *(float4*)&Bs[r][n + 4] = *(const float4*)(p + 4);
    }
    __syncthreads();

#pragma unroll
    for (int k = 0; k < 16; k++) {
      float a[8], b[8];
      *(float4*)&a[0] = *(const float4*)&As[k][tm * 8];
      *(float4*)&a[4] = *(const float4*)&As[k][tm * 8 + 4];
      *(float4*)&b[0] = *(const float4*)&Bs[k][tn * 8];
      *(float4*)&b[4] = *(const float4*)&Bs[k][tn * 8 + 4];
#pragma unroll
      for (int i = 0; i < 8; i++)
#pragma unroll
        for (int j = 0; j < 8; j++) acc[i][j] += a[i] * b[j];
    }
    __syncthreads();
  }

#pragma unroll
  for (int i = 0; i < 8; i++) {
    int row = row0 + tm * 8 + i;
    if (row < NN) {
#pragma unroll
      for (int j = 0; j < 8; j += 4) {
        int col = tn * 8 + j;
        float4 v;
        v.x = fmaxf(acc[i][j + 0] + b1[col + 0], 0.0f);
        v.y = fmaxf(acc[i][j + 1] + b1[col + 1], 0.0f);
        v.z = fmaxf(acc[i][j + 2] + b1[col + 2], 0.0f);
        v.w = fmaxf(acc[i][j + 3] + b1[col + 3], 0.0f);
        *(float4*)(h + (size_t)row * 128 + col) = v;
      }
    }
  }
}

// ---------------------------------------------------------------------------
// GEMM2: [oself | h2] = h @ [ws2 | wn2]   (M=NN, K=128, N=32)
// ---------------------------------------------------------------------------
__global__ __launch_bounds__(256) void gemm2_kernel(
    const float* __restrict__ h, const float* __restrict__ ws2,
    const float* __restrict__ wn2, float* __restrict__ oself,
    float* __restrict__ h2) {
  __shared__ float As[16][132];
  __shared__ float Bs[16][32];

  int tid = threadIdx.x;
  int tn = tid & 15;
  int tm = tid >> 4;
  int row0 = blockIdx.x * 128;

  float acc[8][2];
#pragma unroll
  for (int i = 0; i < 8; i++) { acc[i][0] = 0.0f; acc[i][1] = 0.0f; }

  for (int k0 = 0; k0 < 128; k0 += 16) {
#pragma unroll
    for (int i = 0; i < 2; i++) {
      int flat = tid * 4 + i * 1024;
      int r = flat >> 4;
      int kk = flat & 15;
      int row = row0 + r;
      if (row >= NN) row = NN - 1;
      float4 v = *(const float4*)(h + (size_t)row * 128 + k0 + kk);
      As[kk][r] = v.x; As[kk + 1][r] = v.y;
      As[kk + 2][r] = v.z; As[kk + 3][r] = v.w;
    }
    {
      int flat = tid * 2;
      int r = flat >> 5;
      int c = flat & 31;
      int k = k0 + r;
      float2 v;
      if (c < 16) {
        v = *(const float2*)(ws2 + (size_t)k * 16 + c);
      } else {
        v = *(const float2*)(wn2 + (size_t)k * 16 + (c - 16));
      }
      *(float2*)&Bs[r][c] = v;
    }
    __syncthreads();

#pragma unroll
    for (int k = 0; k < 16; k++) {
      float a[8];
      *(float4*)&a[0] = *(const float4*)&As[k][tm * 8];
      *(float4*)&a[4] = *(const float4*)&As[k][tm * 8 + 4];
      float2 bv = *(const float2*)&Bs[k][tn * 2];
#pragma unroll
      for (int i = 0; i < 8; i++) {
        acc[i][0] += a[i] * bv.x;
        acc[i][1] += a[i] * bv.y;
      }
    }
    __syncthreads();
  }

#pragma unroll
  for (int i = 0; i < 8; i++) {
    int row = row0 + tm * 8 + i;
    if (row < NN) {
      int col = tn * 2;
      float2 v; v.x = acc[i][0]; v.y = acc[i][1];
      if (col < 16) {
        *(float2*)(oself + (size_t)row * 16 + col) = v;
      } else {
        *(float2*)(h2 + (size_t)row * 16 + (col - 16)) = v;
      }
    }
  }
}

// ---------------------------------------------------------------------------
// Layer-2 mean aggregation, gather form: one wave per node,
// 4 edges x 16 cols per iteration, shfl_xor reduce across edge groups.
// ---------------------------------------------------------------------------
__global__ __launch_bounds__(256) void mean2_kernel(
    const float* __restrict__ h2, const int* __restrict__ off,
    const int* __restrict__ deg, const int* __restrict__ perm,
    float* __restrict__ mean2) {
  int node = blockIdx.x * 4 + (threadIdx.x >> 6);
  int lane = threadIdx.x & 63;
  if (node >= NN) return;
  int o = off[node], dg = deg[node];
  int sub = lane >> 4;
  int c = lane & 15;
  float acc = 0.f;
  for (int j = sub; j < dg; j += 4) {
    int s = perm[o + j];
    acc += h2[(size_t)s * 16 + c];
  }
  acc += __shfl_xor(acc, 16);
  acc += __shfl_xor(acc, 32);
  if (sub == 0) {
    float rd = 1.0f / fmaxf((float)dg, 1.0f);
    mean2[(size_t)node * 16 + c] = acc * rd;
  }
}

// ---------------------------------------------------------------------------
// Final: logits = oself + b2 + mean2; out = log_softmax(logits).
// ---------------------------------------------------------------------------
__global__ __launch_bounds__(256) void final_kernel(
    const float* __restrict__ oself, const float* __restrict__ mean2,
    const float* __restrict__ b2, float* __restrict__ out) {
  int i = blockIdx.x * 256 + threadIdx.x;
  if (i >= NN) return;
  float l[16];
  const float4* po = (const float4*)(oself + (size_t)i * 16);
  const float4* pa = (const float4*)(mean2 + (size_t)i * 16);
#pragma unroll
  for (int q = 0; q < 4; q++) {
    float4 o = po[q], a = pa[q];
    l[q * 4 + 0] = o.x + b2[q * 4 + 0] + a.x;
    l[q * 4 + 1] = o.y + b2[q * 4 + 1] + a.y;
    l[q * 4 + 2] = o.z + b2[q * 4 + 2] + a.z;
    l[q * 4 + 3] = o.w + b2[q * 4 + 3] + a.w;
  }
  float m = l[0];
#pragma unroll
  for (int c = 1; c < 16; c++) m = fmaxf(m, l[c]);
  float s = 0.0f;
#pragma unroll
  for (int c = 0; c < 16; c++) s += expf(l[c] - m);
  float ls = logf(s);
  float4* po2 = (float4*)(out + (size_t)i * 16);
#pragma unroll
  for (int q = 0; q < 4; q++) {
    float4 v;
    v.x = l[q * 4 + 0] - m - ls;
    v.y = l[q * 4 + 1] - m - ls;
    v.z = l[q * 4 + 2] - m - ls;
    v.w = l[q * 4 + 3] - m - ls;
    po2[q] = v;
  }
}

// ---------------------------------------------------------------------------
extern "C" void kernel_launch(void* const* d_in, const int* in_sizes, int n_in,
                              void* d_out, int out_size, void* d_ws, size_t ws_size,
                              hipStream_t stream) {
  const float* x   = (const float*)d_in[0];
  const int*   src = (const int*)d_in[1];
  const int*   dst = (const int*)d_in[2];
  const float* ws1 = (const float*)d_in[3];
  const float* wn1 = (const float*)d_in[4];
  const float* b1  = (const float*)d_in[5];
  const float* ws2 = (const float*)d_in[6];
  const float* wn2 = (const float*)d_in[7];
  const float* b2  = (const float*)d_in[8];
  float* out = (float*)d_out;

  // workspace layout
  char* p = (char*)d_ws;
  int* deg  = (int*)p;  p += (size_t)NN * 4;
  int* off  = (int*)p;  p += (size_t)NN * 4;
  int* bcnt = (int*)p;  p += (size_t)((NBUCK + 31) & ~31) * 4;
  int* boff = (int*)p;  p += (size_t)((NBUCK + 32) & ~31) * 4;  // NBUCK+1 used
  int* bcur = (int*)p;  p += (size_t)((NBUCK + 31) & ~31) * 4;
  unsigned int* ebuf = (unsigned int*)p; p += (size_t)NE * 4;
  int* perm = (int*)p;  p += (size_t)NE * 4;
  float* mean1 = (float*)p; p += (size_t)NN * 128 * 4;
  float* h     = mean1;  // alias: gemm1 reads its rows before writing them
  float* h2    = (float*)p; p += (size_t)NN * 16 * 4;
  float* osf   = (float*)p; p += (size_t)NN * 16 * 4;
  float* mean2 = (float*)p; p += (size_t)NN * 16 * 4;

  hipMemsetAsync(deg, 0, (size_t)NN * 4, stream);

  hist_kernel<<<(NE + 255) / 256, 256, 0, stream>>>(dst, deg);
  bsum64_kernel<<<(NBUCK + 3) / 4, 256, 0, stream>>>(deg, bcnt);
  bscan_kernel<<<1, 1024, 0, stream>>>(bcnt, boff, bcur);
  scatter2_kernel<<<(NE + 255) / 256, 256, 0, stream>>>(src, dst, bcur, ebuf);
  bucket_sort_kernel<<<NBUCK, 256, 0, stream>>>(ebuf, boff, deg, off, perm);
  mean1_kernel<<<(NN + 3) / 4, 256, 0, stream>>>(x, off, deg, perm, mean1);
  gemm1_kernel<<<(NN + 127) / 128, 256, 0, stream>>>(x, mean1, ws1, wn1, b1, h);
  gemm2_kernel<<<(NN + 127) / 128, 256, 0, stream>>>(h, ws2, wn2, osf, h2);
  mean2_kernel<<<(NN + 3) / 4, 256, 0, stream>>>(h2, off, deg, perm, mean2);
  final_kernel<<<(NN + 255) / 256, 256, 0, stream>>>(osf, mean2, b2, out);
}

// Round 6
// 412.468 us; speedup vs baseline: 4.3014x; 1.5079x over previous
//
#include <hip/hip_runtime.h>
#include <math.h>

#define NN 100000
#define NE 1600000
#define BSZ 64                          // dst nodes per bucket
#define NBUCK ((NN + BSZ - 1) / BSZ)    // 1563
#define NBLK 256                        // scatter blocks
#define CHUNK ((NE + NBLK - 1) / NBLK)  // 6250 edges per block
#define NH (NBUCK * NBLK)               // 400128 hist entries
#define NSB ((NH + 1023) / 1024)        // 391 scan blocks

// ---------------------------------------------------------------------------
// Pass A: per-block bucket histogram (LDS) + global degree histogram.
// hist[bucket][blk] layout -> bucket-major for the scan.
// ---------------------------------------------------------------------------
__global__ __launch_bounds__(256) void histA_kernel(
    const int* __restrict__ dst, int* __restrict__ deg,
    int* __restrict__ hist) {
  __shared__ int lh[NBUCK];
  int tid = threadIdx.x;
  int b = blockIdx.x;
  for (int i = tid; i < NBUCK; i += 256) lh[i] = 0;
  __syncthreads();
  int e0 = b * CHUNK, e1 = min(e0 + CHUNK, NE);
  for (int e = e0 + tid; e < e1; e += 256) {
    int d = dst[e];
    atomicAdd(&deg[d], 1);       // global int atomic, 100k counters: cheap
    atomicAdd(&lh[d >> 6], 1);   // LDS int atomic, ~4 hits/counter
  }
  __syncthreads();
  for (int i = tid; i < NBUCK; i += 256) hist[i * NBLK + b] = lh[i];
}

// ---------------------------------------------------------------------------
// Multi-block exclusive scan over hist[NH] (in-place), 3 kernels.
// ---------------------------------------------------------------------------
__global__ __launch_bounds__(1024) void scan_sums_kernel(
    const int* __restrict__ hist, int* __restrict__ sums) {
  __shared__ int sdata[1024];
  int i = blockIdx.x * 1024 + threadIdx.x;
  sdata[threadIdx.x] = (i < NH) ? hist[i] : 0;
  __syncthreads();
#pragma unroll
  for (int s = 512; s > 0; s >>= 1) {
    if (threadIdx.x < s) sdata[threadIdx.x] += sdata[threadIdx.x + s];
    __syncthreads();
  }
  if (threadIdx.x == 0) sums[blockIdx.x] = sdata[0];
}

__global__ __launch_bounds__(512) void scan_tops_kernel(int* __restrict__ sums) {
  __shared__ int buf[2][512];
  int tid = threadIdx.x;
  int v = (tid < NSB) ? sums[tid] : 0;
  buf[0][tid] = v;
  __syncthreads();
  int pp = 0;
#pragma unroll
  for (int d = 1; d < 512; d <<= 1) {
    buf[pp ^ 1][tid] = buf[pp][tid] + ((tid >= d) ? buf[pp][tid - d] : 0);
    pp ^= 1;
    __syncthreads();
  }
  if (tid < NSB) sums[tid] = buf[pp][tid] - v;  // exclusive
}

__global__ __launch_bounds__(1024) void scan_apply_kernel(
    int* __restrict__ hist, const int* __restrict__ sums) {
  __shared__ int buf[2][1024];
  int tid = threadIdx.x;
  int i = blockIdx.x * 1024 + tid;
  int v = (i < NH) ? hist[i] : 0;
  buf[0][tid] = v;
  __syncthreads();
  int pp = 0;
#pragma unroll
  for (int d = 1; d < 1024; d <<= 1) {
    buf[pp ^ 1][tid] = buf[pp][tid] + ((tid >= d) ? buf[pp][tid - d] : 0);
    pp ^= 1;
    __syncthreads();
  }
  if (i < NH) hist[i] = sums[blockIdx.x] + buf[pp][tid] - v;  // exclusive
}

// ---------------------------------------------------------------------------
// Pass C: contention-free scatter. Block b loads its cursors from the
// scanned hist, ranks edges with LDS int atomics only, writes ebuf packed
// (dst&63)<<17 | src. Each block's writes per bucket are contiguous runs.
// ---------------------------------------------------------------------------
__global__ __launch_bounds__(256) void scatter3_kernel(
    const int* __restrict__ src, const int* __restrict__ dst,
    const int* __restrict__ scanned, unsigned int* __restrict__ ebuf) {
  __shared__ int cur[NBUCK];
  int tid = threadIdx.x;
  int b = blockIdx.x;
  for (int i = tid; i < NBUCK; i += 256) cur[i] = scanned[i * NBLK + b];
  __syncthreads();
  int e0 = b * CHUNK, e1 = min(e0 + CHUNK, NE);
  for (int e = e0 + tid; e < e1; e += 256) {
    int d = dst[e];
    int p = atomicAdd(&cur[d >> 6], 1);
    ebuf[p] = ((unsigned int)(d & 63) << 17) | (unsigned int)src[e];
  }
}

// ---------------------------------------------------------------------------
// Per-bucket counting sort: bucket-ordered ebuf -> per-node CSR perm + off.
// ---------------------------------------------------------------------------
__global__ __launch_bounds__(256) void bucket_sort_kernel(
    const unsigned int* __restrict__ ebuf, const int* __restrict__ scanned,
    const int* __restrict__ deg, int* __restrict__ off,
    int* __restrict__ perm) {
  __shared__ int loc_off[BSZ];
  __shared__ int cnt[BSZ];
  int tid = threadIdx.x;
  int b = blockIdx.x;
  int e0 = scanned[b * NBLK];
  int e1 = (b + 1 < NBUCK) ? scanned[(b + 1) * NBLK] : NE;

  if (tid < BSZ) {
    int node = b * BSZ + tid;
    int v = (node < NN) ? deg[node] : 0;
    int incl = v;
#pragma unroll
    for (int d = 1; d < 64; d <<= 1) {
      int t = __shfl_up(incl, d);
      if (tid >= d) incl += t;
    }
    int excl = incl - v;
    loc_off[tid] = e0 + excl;
    cnt[tid] = 0;
    if (node < NN) off[node] = e0 + excl;
  }
  __syncthreads();

  for (int e = e0 + tid; e < e1; e += 256) {
    unsigned int pk = ebuf[e];
    int dl = pk >> 17;
    int p = loc_off[dl] + atomicAdd(&cnt[dl], 1);
    perm[p] = (int)(pk & 0x1FFFF);
  }
}

// ---------------------------------------------------------------------------
// Layer-1 mean aggregation, gather form: one wave per node, 2 floats/lane,
// register accumulate (no atomics).
// ---------------------------------------------------------------------------
__global__ __launch_bounds__(256) void mean1_kernel(
    const float* __restrict__ x, const int* __restrict__ off,
    const int* __restrict__ deg, const int* __restrict__ perm,
    float* __restrict__ mean1) {
  int node = blockIdx.x * 4 + (threadIdx.x >> 6);
  int lane = threadIdx.x & 63;
  if (node >= NN) return;
  int o = off[node], dg = deg[node];
  float accx = 0.f, accy = 0.f;
  int j = 0;
  for (; j + 2 <= dg; j += 2) {
    int s0 = perm[o + j], s1 = perm[o + j + 1];
    float2 v0 = *(const float2*)(x + (size_t)s0 * 128 + lane * 2);
    float2 v1 = *(const float2*)(x + (size_t)s1 * 128 + lane * 2);
    accx += v0.x + v1.x;
    accy += v0.y + v1.y;
  }
  if (j < dg) {
    int s0 = perm[o + j];
    float2 v0 = *(const float2*)(x + (size_t)s0 * 128 + lane * 2);
    accx += v0.x;
    accy += v0.y;
  }
  float rd = 1.0f / fmaxf((float)dg, 1.0f);
  float2 r;
  r.x = accx * rd;
  r.y = accy * rd;
  *(float2*)(mean1 + (size_t)node * 128 + lane * 2) = r;
}

// ---------------------------------------------------------------------------
// GEMM1: h = relu([x | mean1] @ [ws1; wn1] + b1)
// M=NN, K=256, N=128. BM=128, BN=128, BK=16, 256 threads, 8x8/thread.
// h aliases mean1 — each block reads only its own 128 rows before writing.
// ---------------------------------------------------------------------------
__global__ __launch_bounds__(256) void gemm1_kernel(
    const float* __restrict__ x, const float* __restrict__ hn,
    const float* __restrict__ ws1, const float* __restrict__ wn1,
    const float* __restrict__ b1, float* __restrict__ h) {
  __shared__ float As[16][132];
  __shared__ float Bs[16][128];

  int tid = threadIdx.x;
  int tn = tid & 15;
  int tm = tid >> 4;
  int row0 = blockIdx.x * 128;

  float acc[8][8];
#pragma unroll
  for (int i = 0; i < 8; i++)
#pragma unroll
    for (int j = 0; j < 8; j++) acc[i][j] = 0.0f;

  for (int k0 = 0; k0 < 256; k0 += 16) {
    bool neigh = (k0 >= 128);
    int kk0 = neigh ? (k0 - 128) : k0;
    const float* Asrc = neigh ? hn : x;
    const float* Bsrc = (neigh ? wn1 : ws1) + (size_t)kk0 * 128;

#pragma unroll
    for (int i = 0; i < 2; i++) {
      int flat = tid * 4 + i * 1024;
      int r = flat >> 4;
      int kk = flat & 15;
      int row = row0 + r;
      if (row >= NN) row = NN - 1;
      float4 v = *(const float4*)(Asrc + (size_t)row * 128 + kk0 + kk);
      As[kk][r] = v.x; As[kk + 1][r] = v.y;
      As[kk + 2][r] = v.z; As[kk + 3][r] = v.w;
    }
    {
      int r = tid >> 4;
      int n = (tid & 15) * 8;
      const float* p = Bsrc + r * 128 + n;
      *(float4*)&Bs[r][n] = *(const float4*)(p);
      *(float4*)&Bs[r][n + 4] = *(const float4*)(p + 4);
    }
    __syncthreads();

#pragma unroll
    for (int k = 0; k < 16; k++) {
      float a[8], b[8];
      *(float4*)&a[0] = *(const float4*)&As[k][tm * 8];
      *(float4*)&a[4] = *(const float4*)&As[k][tm * 8 + 4];
      *(float4*)&b[0] = *(const float4*)&Bs[k][tn * 8];
      *(float4*)&b[4] = *(const float4*)&Bs[k][tn * 8 + 4];
#pragma unroll
      for (int i = 0; i < 8; i++)
#pragma unroll
        for (int j = 0; j < 8; j++) acc[i][j] += a[i] * b[j];
    }
    __syncthreads();
  }

#pragma unroll
  for (int i = 0; i < 8; i++) {
    int row = row0 + tm * 8 + i;
    if (row < NN) {
#pragma unroll
      for (int j = 0; j < 8; j += 4) {
        int col = tn * 8 + j;
        float4 v;
        v.x = fmaxf(acc[i][j + 0] + b1[col + 0], 0.0f);
        v.y = fmaxf(acc[i][j + 1] + b1[col + 1], 0.0f);
        v.z = fmaxf(acc[i][j + 2] + b1[col + 2], 0.0f);
        v.w = fmaxf(acc[i][j + 3] + b1[col + 3], 0.0f);
        *(float4*)(h + (size_t)row * 128 + col) = v;
      }
    }
  }
}

// ---------------------------------------------------------------------------
// GEMM2: [oself | h2] = h @ [ws2 | wn2]   (M=NN, K=128, N=32)
// ---------------------------------------------------------------------------
__global__ __launch_bounds__(256) void gemm2_kernel(
    const float* __restrict__ h, const float* __restrict__ ws2,
    const float* __restrict__ wn2, float* __restrict__ oself,
    float* __restrict__ h2) {
  __shared__ float As[16][132];
  __shared__ float Bs[16][32];

  int tid = threadIdx.x;
  int tn = tid & 15;
  int tm = tid >> 4;
  int row0 = blockIdx.x * 128;

  float acc[8][2];
#pragma unroll
  for (int i = 0; i < 8; i++) { acc[i][0] = 0.0f; acc[i][1] = 0.0f; }

  for (int k0 = 0; k0 < 128; k0 += 16) {
#pragma unroll
    for (int i = 0; i < 2; i++) {
      int flat = tid * 4 + i * 1024;
      int r = flat >> 4;
      int kk = flat & 15;
      int row = row0 + r;
      if (row >= NN) row = NN - 1;
      float4 v = *(const float4*)(h + (size_t)row * 128 + k0 + kk);
      As[kk][r] = v.x; As[kk + 1][r] = v.y;
      As[kk + 2][r] = v.z; As[kk + 3][r] = v.w;
    }
    {
      int flat = tid * 2;
      int r = flat >> 5;
      int c = flat & 31;
      int k = k0 + r;
      float2 v;
      if (c < 16) {
        v = *(const float2*)(ws2 + (size_t)k * 16 + c);
      } else {
        v = *(const float2*)(wn2 + (size_t)k * 16 + (c - 16));
      }
      *(float2*)&Bs[r][c] = v;
    }
    __syncthreads();

#pragma unroll
    for (int k = 0; k < 16; k++) {
      float a[8];
      *(float4*)&a[0] = *(const float4*)&As[k][tm * 8];
      *(float4*)&a[4] = *(const float4*)&As[k][tm * 8 + 4];
      float2 bv = *(const float2*)&Bs[k][tn * 2];
#pragma unroll
      for (int i = 0; i < 8; i++) {
        acc[i][0] += a[i] * bv.x;
        acc[i][1] += a[i] * bv.y;
      }
    }
    __syncthreads();
  }

#pragma unroll
  for (int i = 0; i < 8; i++) {
    int row = row0 + tm * 8 + i;
    if (row < NN) {
      int col = tn * 2;
      float2 v; v.x = acc[i][0]; v.y = acc[i][1];
      if (col < 16) {
        *(float2*)(oself + (size_t)row * 16 + col) = v;
      } else {
        *(float2*)(h2 + (size_t)row * 16 + (col - 16)) = v;
      }
    }
  }
}

// ---------------------------------------------------------------------------
// Layer-2 mean aggregation, gather form: one wave per node,
// 4 edges x 16 cols per iteration, shfl_xor reduce across edge groups.
// ---------------------------------------------------------------------------
__global__ __launch_bounds__(256) void mean2_kernel(
    const float* __restrict__ h2, const int* __restrict__ off,
    const int* __restrict__ deg, const int* __restrict__ perm,
    float* __restrict__ mean2) {
  int node = blockIdx.x * 4 + (threadIdx.x >> 6);
  int lane = threadIdx.x & 63;
  if (node >= NN) return;
  int o = off[node], dg = deg[node];
  int sub = lane >> 4;
  int c = lane & 15;
  float acc = 0.f;
  for (int j = sub; j < dg; j += 4) {
    int s = perm[o + j];
    acc += h2[(size_t)s * 16 + c];
  }
  acc += __shfl_xor(acc, 16);
  acc += __shfl_xor(acc, 32);
  if (sub == 0) {
    float rd = 1.0f / fmaxf((float)dg, 1.0f);
    mean2[(size_t)node * 16 + c] = acc * rd;
  }
}

// ---------------------------------------------------------------------------
// Final: logits = oself + b2 + mean2; out = log_softmax(logits).
// ---------------------------------------------------------------------------
__global__ __launch_bounds__(256) void final_kernel(
    const float* __restrict__ oself, const float* __restrict__ mean2,
    const float* __restrict__ b2, float* __restrict__ out) {
  int i = blockIdx.x * 256 + threadIdx.x;
  if (i >= NN) return;
  float l[16];
  const float4* po = (const float4*)(oself + (size_t)i * 16);
  const float4* pa = (const float4*)(mean2 + (size_t)i * 16);
#pragma unroll
  for (int q = 0; q < 4; q++) {
    float4 o = po[q], a = pa[q];
    l[q * 4 + 0] = o.x + b2[q * 4 + 0] + a.x;
    l[q * 4 + 1] = o.y + b2[q * 4 + 1] + a.y;
    l[q * 4 + 2] = o.z + b2[q * 4 + 2] + a.z;
    l[q * 4 + 3] = o.w + b2[q * 4 + 3] + a.w;
  }
  float m = l[0];
#pragma unroll
  for (int c = 1; c < 16; c++) m = fmaxf(m, l[c]);
  float s = 0.0f;
#pragma unroll
  for (int c = 0; c < 16; c++) s += expf(l[c] - m);
  float ls = logf(s);
  float4* po2 = (float4*)(out + (size_t)i * 16);
#pragma unroll
  for (int q = 0; q < 4; q++) {
    float4 v;
    v.x = l[q * 4 + 0] - m - ls;
    v.y = l[q * 4 + 1] - m - ls;
    v.z = l[q * 4 + 2] - m - ls;
    v.w = l[q * 4 + 3] - m - ls;
    po2[q] = v;
  }
}

// ---------------------------------------------------------------------------
extern "C" void kernel_launch(void* const* d_in, const int* in_sizes, int n_in,
                              void* d_out, int out_size, void* d_ws, size_t ws_size,
                              hipStream_t stream) {
  const float* x   = (const float*)d_in[0];
  const int*   src = (const int*)d_in[1];
  const int*   dst = (const int*)d_in[2];
  const float* ws1 = (const float*)d_in[3];
  const float* wn1 = (const float*)d_in[4];
  const float* b1  = (const float*)d_in[5];
  const float* ws2 = (const float*)d_in[6];
  const float* wn2 = (const float*)d_in[7];
  const float* b2  = (const float*)d_in[8];
  float* out = (float*)d_out;

  // workspace layout
  char* p = (char*)d_ws;
  int* deg  = (int*)p;  p += (size_t)NN * 4;
  int* off  = (int*)p;  p += (size_t)NN * 4;
  int* hist = (int*)p;  p += (size_t)NH * 4;             // scanned in place
  int* sums = (int*)p;  p += (size_t)((NSB + 31) & ~31) * 4;
  unsigned int* ebuf = (unsigned int*)p; p += (size_t)NE * 4;
  int* perm = (int*)p;  p += (size_t)NE * 4;
  float* mean1 = (float*)p; p += (size_t)NN * 128 * 4;
  float* h     = mean1;  // alias: gemm1 reads its rows before writing them
  float* h2    = (float*)p; p += (size_t)NN * 16 * 4;
  float* osf   = (float*)p; p += (size_t)NN * 16 * 4;
  float* mean2 = (float*)p; p += (size_t)NN * 16 * 4;

  hipMemsetAsync(deg, 0, (size_t)NN * 4, stream);

  histA_kernel<<<NBLK, 256, 0, stream>>>(dst, deg, hist);
  scan_sums_kernel<<<NSB, 1024, 0, stream>>>(hist, sums);
  scan_tops_kernel<<<1, 512, 0, stream>>>(sums);
  scan_apply_kernel<<<NSB, 1024, 0, stream>>>(hist, sums);
  scatter3_kernel<<<NBLK, 256, 0, stream>>>(src, dst, hist, ebuf);
  bucket_sort_kernel<<<NBUCK, 256, 0, stream>>>(ebuf, hist, deg, off, perm);
  mean1_kernel<<<(NN + 3) / 4, 256, 0, stream>>>(x, off, deg, perm, mean1);
  gemm1_kernel<<<(NN + 127) / 128, 256, 0, stream>>>(x, mean1, ws1, wn1, b1, h);
  gemm2_kernel<<<(NN + 127) / 128, 256, 0, stream>>>(h, ws2, wn2, osf, h2);
  mean2_kernel<<<(NN + 3) / 4, 256, 0, stream>>>(h2, off, deg, perm, mean2);
  final_kernel<<<(NN + 255) / 256, 256, 0, stream>>>(osf, mean2, b2, out);
}

// Round 7
// 385.758 us; speedup vs baseline: 4.5992x; 1.0692x over previous
//
#include <hip/hip_runtime.h>
#include <math.h>

#define NN 100000
#define NE 1600000
#define BSZ 64                          // dst nodes per bucket
#define NBUCK ((NN + BSZ - 1) / BSZ)    // 1563
#define NBLK 256                        // scatter blocks
#define CHUNK ((NE + NBLK - 1) / NBLK)  // 6250 edges per block
#define NH (NBUCK * NBLK)               // 400128 hist entries
#define NSB ((NH + 1023) / 1024)        // 391 scan blocks

// ---------------------------------------------------------------------------
// Pass A: per-block bucket histogram (LDS) + global degree histogram.
// ---------------------------------------------------------------------------
__global__ __launch_bounds__(256) void histA_kernel(
    const int* __restrict__ dst, int* __restrict__ deg,
    int* __restrict__ hist) {
  __shared__ int lh[NBUCK];
  int tid = threadIdx.x;
  int b = blockIdx.x;
  for (int i = tid; i < NBUCK; i += 256) lh[i] = 0;
  __syncthreads();
  int e0 = b * CHUNK, e1 = min(e0 + CHUNK, NE);
  for (int e = e0 + tid; e < e1; e += 256) {
    int d = dst[e];
    atomicAdd(&deg[d], 1);
    atomicAdd(&lh[d >> 6], 1);
  }
  __syncthreads();
  for (int i = tid; i < NBUCK; i += 256) hist[i * NBLK + b] = lh[i];
}

// ---------------------------------------------------------------------------
// Multi-block exclusive scan over hist[NH] (in-place), 3 kernels.
// ---------------------------------------------------------------------------
__global__ __launch_bounds__(1024) void scan_sums_kernel(
    const int* __restrict__ hist, int* __restrict__ sums) {
  __shared__ int sdata[1024];
  int i = blockIdx.x * 1024 + threadIdx.x;
  sdata[threadIdx.x] = (i < NH) ? hist[i] : 0;
  __syncthreads();
#pragma unroll
  for (int s = 512; s > 0; s >>= 1) {
    if (threadIdx.x < s) sdata[threadIdx.x] += sdata[threadIdx.x + s];
    __syncthreads();
  }
  if (threadIdx.x == 0) sums[blockIdx.x] = sdata[0];
}

__global__ __launch_bounds__(512) void scan_tops_kernel(int* __restrict__ sums) {
  __shared__ int buf[2][512];
  int tid = threadIdx.x;
  int v = (tid < NSB) ? sums[tid] : 0;
  buf[0][tid] = v;
  __syncthreads();
  int pp = 0;
#pragma unroll
  for (int d = 1; d < 512; d <<= 1) {
    buf[pp ^ 1][tid] = buf[pp][tid] + ((tid >= d) ? buf[pp][tid - d] : 0);
    pp ^= 1;
    __syncthreads();
  }
  if (tid < NSB) sums[tid] = buf[pp][tid] - v;  // exclusive
}

__global__ __launch_bounds__(1024) void scan_apply_kernel(
    int* __restrict__ hist, const int* __restrict__ sums) {
  __shared__ int buf[2][1024];
  int tid = threadIdx.x;
  int i = blockIdx.x * 1024 + tid;
  int v = (i < NH) ? hist[i] : 0;
  buf[0][tid] = v;
  __syncthreads();
  int pp = 0;
#pragma unroll
  for (int d = 1; d < 1024; d <<= 1) {
    buf[pp ^ 1][tid] = buf[pp][tid] + ((tid >= d) ? buf[pp][tid - d] : 0);
    pp ^= 1;
    __syncthreads();
  }
  if (i < NH) hist[i] = sums[blockIdx.x] + buf[pp][tid] - v;  // exclusive
}

// ---------------------------------------------------------------------------
// Pass C: contention-free scatter via scanned per-(bucket,block) cursors.
// ---------------------------------------------------------------------------
__global__ __launch_bounds__(256) void scatter3_kernel(
    const int* __restrict__ src, const int* __restrict__ dst,
    const int* __restrict__ scanned, unsigned int* __restrict__ ebuf) {
  __shared__ int cur[NBUCK];
  int tid = threadIdx.x;
  int b = blockIdx.x;
  for (int i = tid; i < NBUCK; i += 256) cur[i] = scanned[i * NBLK + b];
  __syncthreads();
  int e0 = b * CHUNK, e1 = min(e0 + CHUNK, NE);
  for (int e = e0 + tid; e < e1; e += 256) {
    int d = dst[e];
    int p = atomicAdd(&cur[d >> 6], 1);
    ebuf[p] = ((unsigned int)(d & 63) << 17) | (unsigned int)src[e];
  }
}

// ---------------------------------------------------------------------------
// Per-bucket counting sort: bucket-ordered ebuf -> per-node CSR perm + off.
// ---------------------------------------------------------------------------
__global__ __launch_bounds__(256) void bucket_sort_kernel(
    const unsigned int* __restrict__ ebuf, const int* __restrict__ scanned,
    const int* __restrict__ deg, int* __restrict__ off,
    int* __restrict__ perm) {
  __shared__ int loc_off[BSZ];
  __shared__ int cnt[BSZ];
  int tid = threadIdx.x;
  int b = blockIdx.x;
  int e0 = scanned[b * NBLK];
  int e1 = (b + 1 < NBUCK) ? scanned[(b + 1) * NBLK] : NE;

  if (tid < BSZ) {
    int node = b * BSZ + tid;
    int v = (node < NN) ? deg[node] : 0;
    int incl = v;
#pragma unroll
    for (int d = 1; d < 64; d <<= 1) {
      int t = __shfl_up(incl, d);
      if (tid >= d) incl += t;
    }
    int excl = incl - v;
    loc_off[tid] = e0 + excl;
    cnt[tid] = 0;
    if (node < NN) off[node] = e0 + excl;
  }
  __syncthreads();

  for (int e = e0 + tid; e < e1; e += 256) {
    unsigned int pk = ebuf[e];
    int dl = pk >> 17;
    int p = loc_off[dl] + atomicAdd(&cnt[dl], 1);
    perm[p] = (int)(pk & 0x1FFFF);
  }
}

// ---------------------------------------------------------------------------
// Layer-1 mean aggregation: one wave per node, float4/lane (16B),
// 32 lanes per row, 2 edges in parallel (sub=lane>>5), unroll x2
// -> 4 independent 1KB wave-loads in flight.
// ---------------------------------------------------------------------------
__global__ __launch_bounds__(256) void mean1_kernel(
    const float* __restrict__ x, const int* __restrict__ off,
    const int* __restrict__ deg, const int* __restrict__ perm,
    float* __restrict__ mean1) {
  int node = blockIdx.x * 4 + (threadIdx.x >> 6);
  int lane = threadIdx.x & 63;
  if (node >= NN) return;
  int o = off[node], dg = deg[node];
  int sub = lane >> 5;   // which edge of the pair
  int q = lane & 31;     // float4 index within the 128-float row
  float ax = 0.f, ay = 0.f, az = 0.f, aw = 0.f;
  int j = 0;
  for (; j + 4 <= dg; j += 4) {
    int s0 = perm[o + j + sub];
    int s1 = perm[o + j + 2 + sub];
    float4 v0 = *(const float4*)(x + (size_t)s0 * 128 + q * 4);
    float4 v1 = *(const float4*)(x + (size_t)s1 * 128 + q * 4);
    ax += v0.x + v1.x; ay += v0.y + v1.y;
    az += v0.z + v1.z; aw += v0.w + v1.w;
  }
  for (; j + 2 <= dg; j += 2) {
    int s0 = perm[o + j + sub];
    float4 v0 = *(const float4*)(x + (size_t)s0 * 128 + q * 4);
    ax += v0.x; ay += v0.y; az += v0.z; aw += v0.w;
  }
  if (j < dg && sub == 0) {   // odd leftover edge
    int s0 = perm[o + j];
    float4 v0 = *(const float4*)(x + (size_t)s0 * 128 + q * 4);
    ax += v0.x; ay += v0.y; az += v0.z; aw += v0.w;
  }
  // combine the two edge-slots (lane l <-> l^32 hold the same q)
  ax += __shfl_xor(ax, 32); ay += __shfl_xor(ay, 32);
  az += __shfl_xor(az, 32); aw += __shfl_xor(aw, 32);
  if (sub == 0) {
    float rd = 1.0f / fmaxf((float)dg, 1.0f);
    float4 r; r.x = ax * rd; r.y = ay * rd; r.z = az * rd; r.w = aw * rd;
    *(float4*)(mean1 + (size_t)node * 128 + q * 4) = r;
  }
}

// ---------------------------------------------------------------------------
// GEMM1: h = relu([x | mean1] @ [ws1; wn1] + b1)
// M=NN, K=256, N=128. BM=128, BN=128, BK=16, 256 threads, 8x8/thread.
// h aliases mean1 — each block reads only its own 128 rows before writing.
// ---------------------------------------------------------------------------
__global__ __launch_bounds__(256) void gemm1_kernel(
    const float* __restrict__ x, const float* __restrict__ hn,
    const float* __restrict__ ws1, const float* __restrict__ wn1,
    const float* __restrict__ b1, float* __restrict__ h) {
  __shared__ float As[16][132];
  __shared__ float Bs[16][128];

  int tid = threadIdx.x;
  int tn = tid & 15;
  int tm = tid >> 4;
  int row0 = blockIdx.x * 128;

  float acc[8][8];
#pragma unroll
  for (int i = 0; i < 8; i++)
#pragma unroll
    for (int j = 0; j < 8; j++) acc[i][j] = 0.0f;

  for (int k0 = 0; k0 < 256; k0 += 16) {
    bool neigh = (k0 >= 128);
    int kk0 = neigh ? (k0 - 128) : k0;
    const float* Asrc = neigh ? hn : x;
    const float* Bsrc = (neigh ? wn1 : ws1) + (size_t)kk0 * 128;

#pragma unroll
    for (int i = 0; i < 2; i++) {
      int flat = tid * 4 + i * 1024;
      int r = flat >> 4;
      int kk = flat & 15;
      int row = row0 + r;
      if (row >= NN) row = NN - 1;
      float4 v = *(const float4*)(Asrc + (size_t)row * 128 + kk0 + kk);
      As[kk][r] = v.x; As[kk + 1][r] = v.y;
      As[kk + 2][r] = v.z; As[kk + 3][r] = v.w;
    }
    {
      int r = tid >> 4;
      int n = (tid & 15) * 8;
      const float* p = Bsrc + r * 128 + n;
      *(float4*)&Bs[r][n] = *(const float4*)(p);
      *(float4*)&Bs[r][n + 4] = *(const float4*)(p + 4);
    }
    __syncthreads();

#pragma unroll
    for (int k = 0; k < 16; k++) {
      float a[8], b[8];
      *(float4*)&a[0] = *(const float4*)&As[k][tm * 8];
      *(float4*)&a[4] = *(const float4*)&As[k][tm * 8 + 4];
      *(float4*)&b[0] = *(const float4*)&Bs[k][tn * 8];
      *(float4*)&b[4] = *(const float4*)&Bs[k][tn * 8 + 4];
#pragma unroll
      for (int i = 0; i < 8; i++)
#pragma unroll
        for (int j = 0; j < 8; j++) acc[i][j] += a[i] * b[j];
    }
    __syncthreads();
  }

#pragma unroll
  for (int i = 0; i < 8; i++) {
    int row = row0 + tm * 8 + i;
    if (row < NN) {
#pragma unroll
      for (int j = 0; j < 8; j += 4) {
        int col = tn * 8 + j;
        float4 v;
        v.x = fmaxf(acc[i][j + 0] + b1[col + 0], 0.0f);
        v.y = fmaxf(acc[i][j + 1] + b1[col + 1], 0.0f);
        v.z = fmaxf(acc[i][j + 2] + b1[col + 2], 0.0f);
        v.w = fmaxf(acc[i][j + 3] + b1[col + 3], 0.0f);
        *(float4*)(h + (size_t)row * 128 + col) = v;
      }
    }
  }
}

// ---------------------------------------------------------------------------
// GEMM2: [oself | h2] = h @ [ws2 | wn2]   (M=NN, K=128, N=32)
// ---------------------------------------------------------------------------
__global__ __launch_bounds__(256) void gemm2_kernel(
    const float* __restrict__ h, const float* __restrict__ ws2,
    const float* __restrict__ wn2, float* __restrict__ oself,
    float* __restrict__ h2) {
  __shared__ float As[16][132];
  __shared__ float Bs[16][32];

  int tid = threadIdx.x;
  int tn = tid & 15;
  int tm = tid >> 4;
  int row0 = blockIdx.x * 128;

  float acc[8][2];
#pragma unroll
  for (int i = 0; i < 8; i++) { acc[i][0] = 0.0f; acc[i][1] = 0.0f; }

  for (int k0 = 0; k0 < 128; k0 += 16) {
#pragma unroll
    for (int i = 0; i < 2; i++) {
      int flat = tid * 4 + i * 1024;
      int r = flat >> 4;
      int kk = flat & 15;
      int row = row0 + r;
      if (row >= NN) row = NN - 1;
      float4 v = *(const float4*)(h + (size_t)row * 128 + k0 + kk);
      As[kk][r] = v.x; As[kk + 1][r] = v.y;
      As[kk + 2][r] = v.z; As[kk + 3][r] = v.w;
    }
    {
      int flat = tid * 2;
      int r = flat >> 5;
      int c = flat & 31;
      int k = k0 + r;
      float2 v;
      if (c < 16) {
        v = *(const float2*)(ws2 + (size_t)k * 16 + c);
      } else {
        v = *(const float2*)(wn2 + (size_t)k * 16 + (c - 16));
      }
      *(float2*)&Bs[r][c] = v;
    }
    __syncthreads();

#pragma unroll
    for (int k = 0; k < 16; k++) {
      float a[8];
      *(float4*)&a[0] = *(const float4*)&As[k][tm * 8];
      *(float4*)&a[4] = *(const float4*)&As[k][tm * 8 + 4];
      float2 bv = *(const float2*)&Bs[k][tn * 2];
#pragma unroll
      for (int i = 0; i < 8; i++) {
        acc[i][0] += a[i] * bv.x;
        acc[i][1] += a[i] * bv.y;
      }
    }
    __syncthreads();
  }

#pragma unroll
  for (int i = 0; i < 8; i++) {
    int row = row0 + tm * 8 + i;
    if (row < NN) {
      int col = tn * 2;
      float2 v; v.x = acc[i][0]; v.y = acc[i][1];
      if (col < 16) {
        *(float2*)(oself + (size_t)row * 16 + col) = v;
      } else {
        *(float2*)(h2 + (size_t)row * 16 + (col - 16)) = v;
      }
    }
  }
}

// ---------------------------------------------------------------------------
// Layer-2 mean aggregation: one wave per node, float4/lane, 4 lanes/edge,
// 16 edges in parallel; shfl_xor tree reduce (4..32).
// ---------------------------------------------------------------------------
__global__ __launch_bounds__(256) void mean2_kernel(
    const float* __restrict__ h2, const int* __restrict__ off,
    const int* __restrict__ deg, const int* __restrict__ perm,
    float* __restrict__ mean2) {
  int node = blockIdx.x * 4 + (threadIdx.x >> 6);
  int lane = threadIdx.x & 63;
  if (node >= NN) return;
  int o = off[node], dg = deg[node];
  int sub = lane >> 2;   // 16 edge slots
  int q = lane & 3;      // float4 index within the 16-float row
  float ax = 0.f, ay = 0.f, az = 0.f, aw = 0.f;
  for (int j = sub; j < dg; j += 16) {
    int s = perm[o + j];
    float4 v = *(const float4*)(h2 + (size_t)s * 16 + q * 4);
    ax += v.x; ay += v.y; az += v.z; aw += v.w;
  }
#pragma unroll
  for (int d = 4; d <= 32; d <<= 1) {
    ax += __shfl_xor(ax, d); ay += __shfl_xor(ay, d);
    az += __shfl_xor(az, d); aw += __shfl_xor(aw, d);
  }
  if (sub == 0) {
    float rd = 1.0f / fmaxf((float)dg, 1.0f);
    float4 r; r.x = ax * rd; r.y = ay * rd; r.z = az * rd; r.w = aw * rd;
    *(float4*)(mean2 + (size_t)node * 16 + q * 4) = r;
  }
}

// ---------------------------------------------------------------------------
// Final: logits = oself + b2 + mean2; out = log_softmax(logits).
// ---------------------------------------------------------------------------
__global__ __launch_bounds__(256) void final_kernel(
    const float* __restrict__ oself, const float* __restrict__ mean2,
    const float* __restrict__ b2, float* __restrict__ out) {
  int i = blockIdx.x * 256 + threadIdx.x;
  if (i >= NN) return;
  float l[16];
  const float4* po = (const float4*)(oself + (size_t)i * 16);
  const float4* pa = (const float4*)(mean2 + (size_t)i * 16);
#pragma unroll
  for (int q = 0; q < 4; q++) {
    float4 o = po[q], a = pa[q];
    l[q * 4 + 0] = o.x + b2[q * 4 + 0] + a.x;
    l[q * 4 + 1] = o.y + b2[q * 4 + 1] + a.y;
    l[q * 4 + 2] = o.z + b2[q * 4 + 2] + a.z;
    l[q * 4 + 3] = o.w + b2[q * 4 + 3] + a.w;
  }
  float m = l[0];
#pragma unroll
  for (int c = 1; c < 16; c++) m = fmaxf(m, l[c]);
  float s = 0.0f;
#pragma unroll
  for (int c = 0; c < 16; c++) s += expf(l[c] - m);
  float ls = logf(s);
  float4* po2 = (float4*)(out + (size_t)i * 16);
#pragma unroll
  for (int q = 0; q < 4; q++) {
    float4 v;
    v.x = l[q * 4 + 0] - m - ls;
    v.y = l[q * 4 + 1] - m - ls;
    v.z = l[q * 4 + 2] - m - ls;
    v.w = l[q * 4 + 3] - m - ls;
    po2[q] = v;
  }
}

// ---------------------------------------------------------------------------
extern "C" void kernel_launch(void* const* d_in, const int* in_sizes, int n_in,
                              void* d_out, int out_size, void* d_ws, size_t ws_size,
                              hipStream_t stream) {
  const float* x   = (const float*)d_in[0];
  const int*   src = (const int*)d_in[1];
  const int*   dst = (const int*)d_in[2];
  const float* ws1 = (const float*)d_in[3];
  const float* wn1 = (const float*)d_in[4];
  const float* b1  = (const float*)d_in[5];
  const float* ws2 = (const float*)d_in[6];
  const float* wn2 = (const float*)d_in[7];
  const float* b2  = (const float*)d_in[8];
  float* out = (float*)d_out;

  // workspace layout
  char* p = (char*)d_ws;
  int* deg  = (int*)p;  p += (size_t)NN * 4;
  int* off  = (int*)p;  p += (size_t)NN * 4;
  int* hist = (int*)p;  p += (size_t)NH * 4;             // scanned in place
  int* sums = (int*)p;  p += (size_t)((NSB + 31) & ~31) * 4;
  unsigned int* ebuf = (unsigned int*)p; p += (size_t)NE * 4;
  int* perm = (int*)p;  p += (size_t)NE * 4;
  float* mean1 = (float*)p; p += (size_t)NN * 128 * 4;
  float* h     = mean1;  // alias: gemm1 reads its rows before writing them
  float* h2    = (float*)p; p += (size_t)NN * 16 * 4;
  float* osf   = (float*)p; p += (size_t)NN * 16 * 4;
  float* mean2 = (float*)p; p += (size_t)NN * 16 * 4;

  hipMemsetAsync(deg, 0, (size_t)NN * 4, stream);

  histA_kernel<<<NBLK, 256, 0, stream>>>(dst, deg, hist);
  scan_sums_kernel<<<NSB, 1024, 0, stream>>>(hist, sums);
  scan_tops_kernel<<<1, 512, 0, stream>>>(sums);
  scan_apply_kernel<<<NSB, 1024, 0, stream>>>(hist, sums);
  scatter3_kernel<<<NBLK, 256, 0, stream>>>(src, dst, hist, ebuf);
  bucket_sort_kernel<<<NBUCK, 256, 0, stream>>>(ebuf, hist, deg, off, perm);
  mean1_kernel<<<(NN + 3) / 4, 256, 0, stream>>>(x, off, deg, perm, mean1);
  gemm1_kernel<<<(NN + 127) / 128, 256, 0, stream>>>(x, mean1, ws1, wn1, b1, h);
  gemm2_kernel<<<(NN + 127) / 128, 256, 0, stream>>>(h, ws2, wn2, osf, h2);
  mean2_kernel<<<(NN + 3) / 4, 256, 0, stream>>>(h2, off, deg, perm, mean2);
  final_kernel<<<(NN + 255) / 256, 256, 0, stream>>>(osf, mean2, b2, out);
}

// Round 8
// 349.028 us; speedup vs baseline: 5.0832x; 1.1052x over previous
//
#include <hip/hip_runtime.h>
#include <math.h>

#define NN 100000
#define NE 1600000
#define BSZ 64                          // dst nodes per bucket
#define NBUCK ((NN + BSZ - 1) / BSZ)    // 1563
#define NBLK 256                        // scatter blocks
#define CHUNK ((NE + NBLK - 1) / NBLK)  // 6250 edges per block
#define NH (NBUCK * NBLK)               // 400128 hist entries
#define NSB ((NH + 1023) / 1024)        // 391 scan blocks

typedef unsigned int uint;

// bf16 helpers (RNE pack, shift-decode)
__device__ inline uint bf16_1(float f) {
  uint u = __float_as_uint(f);
  return (u + 0x7FFFu + ((u >> 16) & 1u)) >> 16;
}
__device__ inline uint bf16_2(float lo, float hi) {
  return bf16_1(lo) | (bf16_1(hi) << 16);
}
__device__ inline float blo(uint u) { return __uint_as_float(u << 16); }
__device__ inline float bhi(uint u) { return __uint_as_float(u & 0xFFFF0000u); }

// ---------------------------------------------------------------------------
// x (fp32 [NN][128]) -> xh (bf16 pairs, [NN][64] uints). 8 floats/thread.
// ---------------------------------------------------------------------------
__global__ __launch_bounds__(256) void tobf16_kernel(
    const float* __restrict__ x, uint* __restrict__ xh) {
  int i = blockIdx.x * 256 + threadIdx.x;   // 1.6M threads
  if (i >= NN * 16) return;
  const float4* p = (const float4*)x + (size_t)i * 2;
  float4 a = p[0], b = p[1];
  uint4 o;
  o.x = bf16_2(a.x, a.y);
  o.y = bf16_2(a.z, a.w);
  o.z = bf16_2(b.x, b.y);
  o.w = bf16_2(b.z, b.w);
  ((uint4*)xh)[i] = o;
}

// ---------------------------------------------------------------------------
// Pass A: per-block bucket histogram (LDS) + global degree histogram.
// ---------------------------------------------------------------------------
__global__ __launch_bounds__(256) void histA_kernel(
    const int* __restrict__ dst, int* __restrict__ deg,
    int* __restrict__ hist) {
  __shared__ int lh[NBUCK];
  int tid = threadIdx.x;
  int b = blockIdx.x;
  for (int i = tid; i < NBUCK; i += 256) lh[i] = 0;
  __syncthreads();
  int e0 = b * CHUNK, e1 = min(e0 + CHUNK, NE);
  for (int e = e0 + tid; e < e1; e += 256) {
    int d = dst[e];
    atomicAdd(&deg[d], 1);
    atomicAdd(&lh[d >> 6], 1);
  }
  __syncthreads();
  for (int i = tid; i < NBUCK; i += 256) hist[i * NBLK + b] = lh[i];
}

// ---------------------------------------------------------------------------
// Multi-block exclusive scan over hist[NH] (in-place), 3 kernels.
// ---------------------------------------------------------------------------
__global__ __launch_bounds__(1024) void scan_sums_kernel(
    const int* __restrict__ hist, int* __restrict__ sums) {
  __shared__ int sdata[1024];
  int i = blockIdx.x * 1024 + threadIdx.x;
  sdata[threadIdx.x] = (i < NH) ? hist[i] : 0;
  __syncthreads();
#pragma unroll
  for (int s = 512; s > 0; s >>= 1) {
    if (threadIdx.x < s) sdata[threadIdx.x] += sdata[threadIdx.x + s];
    __syncthreads();
  }
  if (threadIdx.x == 0) sums[blockIdx.x] = sdata[0];
}

__global__ __launch_bounds__(512) void scan_tops_kernel(int* __restrict__ sums) {
  __shared__ int buf[2][512];
  int tid = threadIdx.x;
  int v = (tid < NSB) ? sums[tid] : 0;
  buf[0][tid] = v;
  __syncthreads();
  int pp = 0;
#pragma unroll
  for (int d = 1; d < 512; d <<= 1) {
    buf[pp ^ 1][tid] = buf[pp][tid] + ((tid >= d) ? buf[pp][tid - d] : 0);
    pp ^= 1;
    __syncthreads();
  }
  if (tid < NSB) sums[tid] = buf[pp][tid] - v;  // exclusive
}

__global__ __launch_bounds__(1024) void scan_apply_kernel(
    int* __restrict__ hist, const int* __restrict__ sums) {
  __shared__ int buf[2][1024];
  int tid = threadIdx.x;
  int i = blockIdx.x * 1024 + tid;
  int v = (i < NH) ? hist[i] : 0;
  buf[0][tid] = v;
  __syncthreads();
  int pp = 0;
#pragma unroll
  for (int d = 1; d < 1024; d <<= 1) {
    buf[pp ^ 1][tid] = buf[pp][tid] + ((tid >= d) ? buf[pp][tid - d] : 0);
    pp ^= 1;
    __syncthreads();
  }
  if (i < NH) hist[i] = sums[blockIdx.x] + buf[pp][tid] - v;  // exclusive
}

// ---------------------------------------------------------------------------
// Pass C: contention-free scatter via scanned per-(bucket,block) cursors.
// ---------------------------------------------------------------------------
__global__ __launch_bounds__(256) void scatter3_kernel(
    const int* __restrict__ src, const int* __restrict__ dst,
    const int* __restrict__ scanned, unsigned int* __restrict__ ebuf) {
  __shared__ int cur[NBUCK];
  int tid = threadIdx.x;
  int b = blockIdx.x;
  for (int i = tid; i < NBUCK; i += 256) cur[i] = scanned[i * NBLK + b];
  __syncthreads();
  int e0 = b * CHUNK, e1 = min(e0 + CHUNK, NE);
  for (int e = e0 + tid; e < e1; e += 256) {
    int d = dst[e];
    int p = atomicAdd(&cur[d >> 6], 1);
    ebuf[p] = ((unsigned int)(d & 63) << 17) | (unsigned int)src[e];
  }
}

// ---------------------------------------------------------------------------
// Per-bucket counting sort: bucket-ordered ebuf -> per-node CSR perm + off.
// ---------------------------------------------------------------------------
__global__ __launch_bounds__(256) void bucket_sort_kernel(
    const unsigned int* __restrict__ ebuf, const int* __restrict__ scanned,
    const int* __restrict__ deg, int* __restrict__ off,
    int* __restrict__ perm) {
  __shared__ int loc_off[BSZ];
  __shared__ int cnt[BSZ];
  int tid = threadIdx.x;
  int b = blockIdx.x;
  int e0 = scanned[b * NBLK];
  int e1 = (b + 1 < NBUCK) ? scanned[(b + 1) * NBLK] : NE;

  if (tid < BSZ) {
    int node = b * BSZ + tid;
    int v = (node < NN) ? deg[node] : 0;
    int incl = v;
#pragma unroll
    for (int d = 1; d < 64; d <<= 1) {
      int t = __shfl_up(incl, d);
      if (tid >= d) incl += t;
    }
    int excl = incl - v;
    loc_off[tid] = e0 + excl;
    cnt[tid] = 0;
    if (node < NN) off[node] = e0 + excl;
  }
  __syncthreads();

  for (int e = e0 + tid; e < e1; e += 256) {
    unsigned int pk = ebuf[e];
    int dl = pk >> 17;
    int p = loc_off[dl] + atomicAdd(&cnt[dl], 1);
    perm[p] = (int)(pk & 0x1FFFF);
  }
}

// ---------------------------------------------------------------------------
// Layer-1 mean aggregation from bf16 rows (256B): one wave per node,
// uint4 (8 bf16) per lane, 16 lanes per row, 4 edges in parallel,
// unroll x2 -> 8 independent gathers in flight. fp32 accumulate.
// ---------------------------------------------------------------------------
__global__ __launch_bounds__(256) void mean1_kernel(
    const uint* __restrict__ xh, const int* __restrict__ off,
    const int* __restrict__ deg, const int* __restrict__ perm,
    float* __restrict__ mean1) {
  int node = blockIdx.x * 4 + (threadIdx.x >> 6);
  int lane = threadIdx.x & 63;
  if (node >= NN) return;
  int o = off[node], dg = deg[node];
  int sub = lane >> 4;   // 4 edge slots
  int q = lane & 15;     // which uint4 (8 bf16) of the 64-uint row
  float a0 = 0.f, a1 = 0.f, a2 = 0.f, a3 = 0.f;
  float a4 = 0.f, a5 = 0.f, a6 = 0.f, a7 = 0.f;
  int j = sub;
  for (; j + 4 < dg; j += 8) {
    int s0 = perm[o + j];
    int s1 = perm[o + j + 4];
    uint4 v0 = *(const uint4*)(xh + (size_t)s0 * 64 + q * 4);
    uint4 v1 = *(const uint4*)(xh + (size_t)s1 * 64 + q * 4);
    a0 += blo(v0.x) + blo(v1.x); a1 += bhi(v0.x) + bhi(v1.x);
    a2 += blo(v0.y) + blo(v1.y); a3 += bhi(v0.y) + bhi(v1.y);
    a4 += blo(v0.z) + blo(v1.z); a5 += bhi(v0.z) + bhi(v1.z);
    a6 += blo(v0.w) + blo(v1.w); a7 += bhi(v0.w) + bhi(v1.w);
  }
  if (j < dg) {
    int s0 = perm[o + j];
    uint4 v0 = *(const uint4*)(xh + (size_t)s0 * 64 + q * 4);
    a0 += blo(v0.x); a1 += bhi(v0.x);
    a2 += blo(v0.y); a3 += bhi(v0.y);
    a4 += blo(v0.z); a5 += bhi(v0.z);
    a6 += blo(v0.w); a7 += bhi(v0.w);
  }
  // reduce the 4 edge slots (xor 16, 32)
#pragma unroll
  for (int d = 16; d <= 32; d <<= 1) {
    a0 += __shfl_xor(a0, d); a1 += __shfl_xor(a1, d);
    a2 += __shfl_xor(a2, d); a3 += __shfl_xor(a3, d);
    a4 += __shfl_xor(a4, d); a5 += __shfl_xor(a5, d);
    a6 += __shfl_xor(a6, d); a7 += __shfl_xor(a7, d);
  }
  if (sub == 0) {
    float rd = 1.0f / fmaxf((float)dg, 1.0f);
    float4 r0, r1;
    r0.x = a0 * rd; r0.y = a1 * rd; r0.z = a2 * rd; r0.w = a3 * rd;
    r1.x = a4 * rd; r1.y = a5 * rd; r1.z = a6 * rd; r1.w = a7 * rd;
    float* pm = mean1 + (size_t)node * 128 + q * 8;
    *(float4*)pm = r0;
    *(float4*)(pm + 4) = r1;
  }
}

// ---------------------------------------------------------------------------
// GEMM1: h = relu([x | mean1] @ [ws1; wn1] + b1)
// M=NN, K=256, N=128. BM=128, BN=128, BK=16, 256 threads, 8x8/thread.
// h aliases mean1 — each block reads only its own 128 rows before writing.
// ---------------------------------------------------------------------------
__global__ __launch_bounds__(256) void gemm1_kernel(
    const float* __restrict__ x, const float* __restrict__ hn,
    const float* __restrict__ ws1, const float* __restrict__ wn1,
    const float* __restrict__ b1, float* __restrict__ h) {
  __shared__ float As[16][132];
  __shared__ float Bs[16][128];

  int tid = threadIdx.x;
  int tn = tid & 15;
  int tm = tid >> 4;
  int row0 = blockIdx.x * 128;

  float acc[8][8];
#pragma unroll
  for (int i = 0; i < 8; i++)
#pragma unroll
    for (int j = 0; j < 8; j++) acc[i][j] = 0.0f;

  for (int k0 = 0; k0 < 256; k0 += 16) {
    bool neigh = (k0 >= 128);
    int kk0 = neigh ? (k0 - 128) : k0;
    const float* Asrc = neigh ? hn : x;
    const float* Bsrc = (neigh ? wn1 : ws1) + (size_t)kk0 * 128;

#pragma unroll
    for (int i = 0; i < 2; i++) {
      int flat = tid * 4 + i * 1024;
      int r = flat >> 4;
      int kk = flat & 15;
      int row = row0 + r;
      if (row >= NN) row = NN - 1;
      float4 v = *(const float4*)(Asrc + (size_t)row * 128 + kk0 + kk);
      As[kk][r] = v.x; As[kk + 1][r] = v.y;
      As[kk + 2][r] = v.z; As[kk + 3][r] = v.w;
    }
    {
      int r = tid >> 4;
      int n = (tid & 15) * 8;
      const float* p = Bsrc + r * 128 + n;
      *(float4*)&Bs[r][n] = *(const float4*)(p);
      *(float4*)&Bs[r][n + 4] = *(const float4*)(p + 4);
    }
    __syncthreads();

#pragma unroll
    for (int k = 0; k < 16; k++) {
      float a[8], b[8];
      *(float4*)&a[0] = *(const float4*)&As[k][tm * 8];
      *(float4*)&a[4] = *(const float4*)&As[k][tm * 8 + 4];
      *(float4*)&b[0] = *(const float4*)&Bs[k][tn * 8];
      *(float4*)&b[4] = *(const float4*)&Bs[k][tn * 8 + 4];
#pragma unroll
      for (int i = 0; i < 8; i++)
#pragma unroll
        for (int j = 0; j < 8; j++) acc[i][j] += a[i] * b[j];
    }
    __syncthreads();
  }

#pragma unroll
  for (int i = 0; i < 8; i++) {
    int row = row0 + tm * 8 + i;
    if (row < NN) {
#pragma unroll
      for (int j = 0; j < 8; j += 4) {
        int col = tn * 8 + j;
        float4 v;
        v.x = fmaxf(acc[i][j + 0] + b1[col + 0], 0.0f);
        v.y = fmaxf(acc[i][j + 1] + b1[col + 1], 0.0f);
        v.z = fmaxf(acc[i][j + 2] + b1[col + 2], 0.0f);
        v.w = fmaxf(acc[i][j + 3] + b1[col + 3], 0.0f);
        *(float4*)(h + (size_t)row * 128 + col) = v;
      }
    }
  }
}

// ---------------------------------------------------------------------------
// GEMM2: [oself | h2] = h @ [ws2 | wn2]   (M=NN, K=128, N=32)
// ---------------------------------------------------------------------------
__global__ __launch_bounds__(256) void gemm2_kernel(
    const float* __restrict__ h, const float* __restrict__ ws2,
    const float* __restrict__ wn2, float* __restrict__ oself,
    float* __restrict__ h2) {
  __shared__ float As[16][132];
  __shared__ float Bs[16][32];

  int tid = threadIdx.x;
  int tn = tid & 15;
  int tm = tid >> 4;
  int row0 = blockIdx.x * 128;

  float acc[8][2];
#pragma unroll
  for (int i = 0; i < 8; i++) { acc[i][0] = 0.0f; acc[i][1] = 0.0f; }

  for (int k0 = 0; k0 < 128; k0 += 16) {
#pragma unroll
    for (int i = 0; i < 2; i++) {
      int flat = tid * 4 + i * 1024;
      int r = flat >> 4;
      int kk = flat & 15;
      int row = row0 + r;
      if (row >= NN) row = NN - 1;
      float4 v = *(const float4*)(h + (size_t)row * 128 + k0 + kk);
      As[kk][r] = v.x; As[kk + 1][r] = v.y;
      As[kk + 2][r] = v.z; As[kk + 3][r] = v.w;
    }
    {
      int flat = tid * 2;
      int r = flat >> 5;
      int c = flat & 31;
      int k = k0 + r;
      float2 v;
      if (c < 16) {
        v = *(const float2*)(ws2 + (size_t)k * 16 + c);
      } else {
        v = *(const float2*)(wn2 + (size_t)k * 16 + (c - 16));
      }
      *(float2*)&Bs[r][c] = v;
    }
    __syncthreads();

#pragma unroll
    for (int k = 0; k < 16; k++) {
      float a[8];
      *(float4*)&a[0] = *(const float4*)&As[k][tm * 8];
      *(float4*)&a[4] = *(const float4*)&As[k][tm * 8 + 4];
      float2 bv = *(const float2*)&Bs[k][tn * 2];
#pragma unroll
      for (int i = 0; i < 8; i++) {
        acc[i][0] += a[i] * bv.x;
        acc[i][1] += a[i] * bv.y;
      }
    }
    __syncthreads();
  }

#pragma unroll
  for (int i = 0; i < 8; i++) {
    int row = row0 + tm * 8 + i;
    if (row < NN) {
      int col = tn * 2;
      float2 v; v.x = acc[i][0]; v.y = acc[i][1];
      if (col < 16) {
        *(float2*)(oself + (size_t)row * 16 + col) = v;
      } else {
        *(float2*)(h2 + (size_t)row * 16 + (col - 16)) = v;
      }
    }
  }
}

// ---------------------------------------------------------------------------
// Layer-2 mean aggregation: one wave per node, float4/lane, 4 lanes/edge,
// 16 edges in parallel; shfl_xor tree reduce (4..32).
// ---------------------------------------------------------------------------
__global__ __launch_bounds__(256) void mean2_kernel(
    const float* __restrict__ h2, const int* __restrict__ off,
    const int* __restrict__ deg, const int* __restrict__ perm,
    float* __restrict__ mean2) {
  int node = blockIdx.x * 4 + (threadIdx.x >> 6);
  int lane = threadIdx.x & 63;
  if (node >= NN) return;
  int o = off[node], dg = deg[node];
  int sub = lane >> 2;   // 16 edge slots
  int q = lane & 3;      // float4 index within the 16-float row
  float ax = 0.f, ay = 0.f, az = 0.f, aw = 0.f;
  for (int j = sub; j < dg; j += 16) {
    int s = perm[o + j];
    float4 v = *(const float4*)(h2 + (size_t)s * 16 + q * 4);
    ax += v.x; ay += v.y; az += v.z; aw += v.w;
  }
#pragma unroll
  for (int d = 4; d <= 32; d <<= 1) {
    ax += __shfl_xor(ax, d); ay += __shfl_xor(ay, d);
    az += __shfl_xor(az, d); aw += __shfl_xor(aw, d);
  }
  if (sub == 0) {
    float rd = 1.0f / fmaxf((float)dg, 1.0f);
    float4 r; r.x = ax * rd; r.y = ay * rd; r.z = az * rd; r.w = aw * rd;
    *(float4*)(mean2 + (size_t)node * 16 + q * 4) = r;
  }
}

// ---------------------------------------------------------------------------
// Final: logits = oself + b2 + mean2; out = log_softmax(logits).
// ---------------------------------------------------------------------------
__global__ __launch_bounds__(256) void final_kernel(
    const float* __restrict__ oself, const float* __restrict__ mean2,
    const float* __restrict__ b2, float* __restrict__ out) {
  int i = blockIdx.x * 256 + threadIdx.x;
  if (i >= NN) return;
  float l[16];
  const float4* po = (const float4*)(oself + (size_t)i * 16);
  const float4* pa = (const float4*)(mean2 + (size_t)i * 16);
#pragma unroll
  for (int q = 0; q < 4; q++) {
    float4 o = po[q], a = pa[q];
    l[q * 4 + 0] = o.x + b2[q * 4 + 0] + a.x;
    l[q * 4 + 1] = o.y + b2[q * 4 + 1] + a.y;
    l[q * 4 + 2] = o.z + b2[q * 4 + 2] + a.z;
    l[q * 4 + 3] = o.w + b2[q * 4 + 3] + a.w;
  }
  float m = l[0];
#pragma unroll
  for (int c = 1; c < 16; c++) m = fmaxf(m, l[c]);
  float s = 0.0f;
#pragma unroll
  for (int c = 0; c < 16; c++) s += expf(l[c] - m);
  float ls = logf(s);
  float4* po2 = (float4*)(out + (size_t)i * 16);
#pragma unroll
  for (int q = 0; q < 4; q++) {
    float4 v;
    v.x = l[q * 4 + 0] - m - ls;
    v.y = l[q * 4 + 1] - m - ls;
    v.z = l[q * 4 + 2] - m - ls;
    v.w = l[q * 4 + 3] - m - ls;
    po2[q] = v;
  }
}

// ---------------------------------------------------------------------------
extern "C" void kernel_launch(void* const* d_in, const int* in_sizes, int n_in,
                              void* d_out, int out_size, void* d_ws, size_t ws_size,
                              hipStream_t stream) {
  const float* x   = (const float*)d_in[0];
  const int*   src = (const int*)d_in[1];
  const int*   dst = (const int*)d_in[2];
  const float* ws1 = (const float*)d_in[3];
  const float* wn1 = (const float*)d_in[4];
  const float* b1  = (const float*)d_in[5];
  const float* ws2 = (const float*)d_in[6];
  const float* wn2 = (const float*)d_in[7];
  const float* b2  = (const float*)d_in[8];
  float* out = (float*)d_out;

  // workspace layout
  char* p = (char*)d_ws;
  int* deg  = (int*)p;  p += (size_t)NN * 4;
  int* off  = (int*)p;  p += (size_t)NN * 4;
  int* hist = (int*)p;  p += (size_t)NH * 4;             // scanned in place
  int* sums = (int*)p;  p += (size_t)((NSB + 31) & ~31) * 4;
  unsigned int* ebuf = (unsigned int*)p; p += (size_t)NE * 4;
  int* perm = (int*)p;  p += (size_t)NE * 4;
  uint* xh  = (uint*)p; p += (size_t)NN * 64 * 4;        // bf16 copy of x
  float* mean1 = (float*)p; p += (size_t)NN * 128 * 4;
  float* h     = mean1;  // alias: gemm1 reads its rows before writing them
  float* h2    = (float*)p; p += (size_t)NN * 16 * 4;
  float* osf   = (float*)p; p += (size_t)NN * 16 * 4;
  float* mean2 = (float*)p; p += (size_t)NN * 16 * 4;

  hipMemsetAsync(deg, 0, (size_t)NN * 4, stream);

  tobf16_kernel<<<(NN * 16 + 255) / 256, 256, 0, stream>>>(x, xh);
  histA_kernel<<<NBLK, 256, 0, stream>>>(dst, deg, hist);
  scan_sums_kernel<<<NSB, 1024, 0, stream>>>(hist, sums);
  scan_tops_kernel<<<1, 512, 0, stream>>>(sums);
  scan_apply_kernel<<<NSB, 1024, 0, stream>>>(hist, sums);
  scatter3_kernel<<<NBLK, 256, 0, stream>>>(src, dst, hist, ebuf);
  bucket_sort_kernel<<<NBUCK, 256, 0, stream>>>(ebuf, hist, deg, off, perm);
  mean1_kernel<<<(NN + 3) / 4, 256, 0, stream>>>(xh, off, deg, perm, mean1);
  gemm1_kernel<<<(NN + 127) / 128, 256, 0, stream>>>(x, mean1, ws1, wn1, b1, h);
  gemm2_kernel<<<(NN + 127) / 128, 256, 0, stream>>>(h, ws2, wn2, osf, h2);
  mean2_kernel<<<(NN + 3) / 4, 256, 0, stream>>>(h2, off, deg, perm, mean2);
  final_kernel<<<(NN + 255) / 256, 256, 0, stream>>>(osf, mean2, b2, out);
}

// Round 9
// 296.785 us; speedup vs baseline: 5.9780x; 1.1760x over previous
//
#include <hip/hip_runtime.h>
#include <math.h>

#define NN 100000
#define NE 1600000
#define BSZ 64                          // dst nodes per bucket
#define NBUCK ((NN + BSZ - 1) / BSZ)    // 1563
#define NBLK 256                        // scatter blocks
#define CHUNK ((NE + NBLK - 1) / NBLK)  // 6250 edges per block
#define NH (NBUCK * NBLK)               // 400128 hist entries
#define NSB ((NH + 1023) / 1024)        // 391 scan blocks

typedef unsigned int uint;
typedef unsigned short ushort_t;
typedef float f32x4 __attribute__((ext_vector_type(4)));
typedef short s16x8 __attribute__((ext_vector_type(8)));

union U4S8 { uint4 u; s16x8 s; };

// bf16 helpers (RNE pack, shift-decode)
__device__ inline uint bf16_1(float f) {
  uint u = __float_as_uint(f);
  return (u + 0x7FFFu + ((u >> 16) & 1u)) >> 16;
}
__device__ inline uint bf16_2(float lo, float hi) {
  return bf16_1(lo) | (bf16_1(hi) << 16);
}
__device__ inline float blo(uint u) { return __uint_as_float(u << 16); }
__device__ inline float bhi(uint u) { return __uint_as_float(u & 0xFFFF0000u); }

__device__ inline f32x4 mfma_bf16(uint4 a, uint4 b, f32x4 c) {
  U4S8 ua, ub; ua.u = a; ub.u = b;
  return __builtin_amdgcn_mfma_f32_16x16x32_bf16(ua.s, ub.s, c, 0, 0, 0);
}

// ---------------------------------------------------------------------------
// x (fp32 [NN][128]) -> xh (bf16 pairs, [NN][64] uints). 8 floats/thread.
// ---------------------------------------------------------------------------
__global__ __launch_bounds__(256) void tobf16_kernel(
    const float* __restrict__ x, uint* __restrict__ xh) {
  int i = blockIdx.x * 256 + threadIdx.x;
  if (i >= NN * 16) return;
  const float4* p = (const float4*)x + (size_t)i * 2;
  float4 a = p[0], b = p[1];
  uint4 o;
  o.x = bf16_2(a.x, a.y);
  o.y = bf16_2(a.z, a.w);
  o.z = bf16_2(b.x, b.y);
  o.w = bf16_2(b.z, b.w);
  ((uint4*)xh)[i] = o;
}

// ---------------------------------------------------------------------------
// Weight prep: w1t[col][k] = bf16([ws1;wn1][k][col]), K=256 -> 128 uints/row.
// ---------------------------------------------------------------------------
__global__ __launch_bounds__(256) void prep_w1_kernel(
    const float* __restrict__ ws1, const float* __restrict__ wn1,
    uint* __restrict__ w1t) {
  int idx = blockIdx.x * 256 + threadIdx.x;   // 128 cols * 128 uints
  if (idx >= 128 * 128) return;
  int col = idx >> 7, ku = idx & 127;
  int k = ku * 2;
  const float* w = (k < 128) ? ws1 : wn1;
  int kk = (k < 128) ? k : (k - 128);
  w1t[idx] = bf16_2(w[(size_t)kk * 128 + col], w[(size_t)(kk + 1) * 128 + col]);
}

// w2t[col][k] = bf16([ws2|wn2][k][col]), cols 0..15 = ws2, 16..31 = wn2, K=128.
__global__ __launch_bounds__(256) void prep_w2_kernel(
    const float* __restrict__ ws2, const float* __restrict__ wn2,
    uint* __restrict__ w2t) {
  int idx = blockIdx.x * 256 + threadIdx.x;   // 32 cols * 64 uints
  if (idx >= 32 * 64) return;
  int col = idx >> 6, ku = idx & 63;
  int k = ku * 2;
  const float* w = (col < 16) ? ws2 : wn2;
  int c = col & 15;
  w2t[idx] = bf16_2(w[(size_t)k * 16 + c], w[(size_t)(k + 1) * 16 + c]);
}

// ---------------------------------------------------------------------------
// Pass A: per-block bucket histogram (LDS) + global degree histogram.
// ---------------------------------------------------------------------------
__global__ __launch_bounds__(256) void histA_kernel(
    const int* __restrict__ dst, int* __restrict__ deg,
    int* __restrict__ hist) {
  __shared__ int lh[NBUCK];
  int tid = threadIdx.x;
  int b = blockIdx.x;
  for (int i = tid; i < NBUCK; i += 256) lh[i] = 0;
  __syncthreads();
  int e0 = b * CHUNK, e1 = min(e0 + CHUNK, NE);
  for (int e = e0 + tid; e < e1; e += 256) {
    int d = dst[e];
    atomicAdd(&deg[d], 1);
    atomicAdd(&lh[d >> 6], 1);
  }
  __syncthreads();
  for (int i = tid; i < NBUCK; i += 256) hist[i * NBLK + b] = lh[i];
}

// ---------------------------------------------------------------------------
// Multi-block exclusive scan over hist[NH] (in-place), 3 kernels.
// ---------------------------------------------------------------------------
__global__ __launch_bounds__(1024) void scan_sums_kernel(
    const int* __restrict__ hist, int* __restrict__ sums) {
  __shared__ int sdata[1024];
  int i = blockIdx.x * 1024 + threadIdx.x;
  sdata[threadIdx.x] = (i < NH) ? hist[i] : 0;
  __syncthreads();
#pragma unroll
  for (int s = 512; s > 0; s >>= 1) {
    if (threadIdx.x < s) sdata[threadIdx.x] += sdata[threadIdx.x + s];
    __syncthreads();
  }
  if (threadIdx.x == 0) sums[blockIdx.x] = sdata[0];
}

__global__ __launch_bounds__(512) void scan_tops_kernel(int* __restrict__ sums) {
  __shared__ int buf[2][512];
  int tid = threadIdx.x;
  int v = (tid < NSB) ? sums[tid] : 0;
  buf[0][tid] = v;
  __syncthreads();
  int pp = 0;
#pragma unroll
  for (int d = 1; d < 512; d <<= 1) {
    buf[pp ^ 1][tid] = buf[pp][tid] + ((tid >= d) ? buf[pp][tid - d] : 0);
    pp ^= 1;
    __syncthreads();
  }
  if (tid < NSB) sums[tid] = buf[pp][tid] - v;  // exclusive
}

__global__ __launch_bounds__(1024) void scan_apply_kernel(
    int* __restrict__ hist, const int* __restrict__ sums) {
  __shared__ int buf[2][1024];
  int tid = threadIdx.x;
  int i = blockIdx.x * 1024 + tid;
  int v = (i < NH) ? hist[i] : 0;
  buf[0][tid] = v;
  __syncthreads();
  int pp = 0;
#pragma unroll
  for (int d = 1; d < 1024; d <<= 1) {
    buf[pp ^ 1][tid] = buf[pp][tid] + ((tid >= d) ? buf[pp][tid - d] : 0);
    pp ^= 1;
    __syncthreads();
  }
  if (i < NH) hist[i] = sums[blockIdx.x] + buf[pp][tid] - v;  // exclusive
}

// ---------------------------------------------------------------------------
// Pass C: contention-free scatter via scanned per-(bucket,block) cursors.
// ---------------------------------------------------------------------------
__global__ __launch_bounds__(256) void scatter3_kernel(
    const int* __restrict__ src, const int* __restrict__ dst,
    const int* __restrict__ scanned, unsigned int* __restrict__ ebuf) {
  __shared__ int cur[NBUCK];
  int tid = threadIdx.x;
  int b = blockIdx.x;
  for (int i = tid; i < NBUCK; i += 256) cur[i] = scanned[i * NBLK + b];
  __syncthreads();
  int e0 = b * CHUNK, e1 = min(e0 + CHUNK, NE);
  for (int e = e0 + tid; e < e1; e += 256) {
    int d = dst[e];
    int p = atomicAdd(&cur[d >> 6], 1);
    ebuf[p] = ((unsigned int)(d & 63) << 17) | (unsigned int)src[e];
  }
}

// ---------------------------------------------------------------------------
// Per-bucket counting sort: bucket-ordered ebuf -> per-node CSR perm + off.
// ---------------------------------------------------------------------------
__global__ __launch_bounds__(256) void bucket_sort_kernel(
    const unsigned int* __restrict__ ebuf, const int* __restrict__ scanned,
    const int* __restrict__ deg, int* __restrict__ off,
    int* __restrict__ perm) {
  __shared__ int loc_off[BSZ];
  __shared__ int cnt[BSZ];
  int tid = threadIdx.x;
  int b = blockIdx.x;
  int e0 = scanned[b * NBLK];
  int e1 = (b + 1 < NBUCK) ? scanned[(b + 1) * NBLK] : NE;

  if (tid < BSZ) {
    int node = b * BSZ + tid;
    int v = (node < NN) ? deg[node] : 0;
    int incl = v;
#pragma unroll
    for (int d = 1; d < 64; d <<= 1) {
      int t = __shfl_up(incl, d);
      if (tid >= d) incl += t;
    }
    int excl = incl - v;
    loc_off[tid] = e0 + excl;
    cnt[tid] = 0;
    if (node < NN) off[node] = e0 + excl;
  }
  __syncthreads();

  for (int e = e0 + tid; e < e1; e += 256) {
    unsigned int pk = ebuf[e];
    int dl = pk >> 17;
    int p = loc_off[dl] + atomicAdd(&cnt[dl], 1);
    perm[p] = (int)(pk & 0x1FFFF);
  }
}

// ---------------------------------------------------------------------------
// Layer-1 mean aggregation from bf16 rows (256B): one wave per node,
// uint4 (8 bf16) per lane, 16 lanes per row, 4 edges in parallel,
// fp32 accumulate, bf16 output (feeds MFMA GEMM1 directly).
// ---------------------------------------------------------------------------
__global__ __launch_bounds__(256) void mean1_kernel(
    const uint* __restrict__ xh, const int* __restrict__ off,
    const int* __restrict__ deg, const int* __restrict__ perm,
    uint* __restrict__ mean1h) {
  int node = blockIdx.x * 4 + (threadIdx.x >> 6);
  int lane = threadIdx.x & 63;
  if (node >= NN) return;
  int o = off[node], dg = deg[node];
  int sub = lane >> 4;   // 4 edge slots
  int q = lane & 15;     // which uint4 (8 bf16) of the 64-uint row
  float a0 = 0.f, a1 = 0.f, a2 = 0.f, a3 = 0.f;
  float a4 = 0.f, a5 = 0.f, a6 = 0.f, a7 = 0.f;
  int j = sub;
  for (; j + 4 < dg; j += 8) {
    int s0 = perm[o + j];
    int s1 = perm[o + j + 4];
    uint4 v0 = *(const uint4*)(xh + (size_t)s0 * 64 + q * 4);
    uint4 v1 = *(const uint4*)(xh + (size_t)s1 * 64 + q * 4);
    a0 += blo(v0.x) + blo(v1.x); a1 += bhi(v0.x) + bhi(v1.x);
    a2 += blo(v0.y) + blo(v1.y); a3 += bhi(v0.y) + bhi(v1.y);
    a4 += blo(v0.z) + blo(v1.z); a5 += bhi(v0.z) + bhi(v1.z);
    a6 += blo(v0.w) + blo(v1.w); a7 += bhi(v0.w) + bhi(v1.w);
  }
  if (j < dg) {
    int s0 = perm[o + j];
    uint4 v0 = *(const uint4*)(xh + (size_t)s0 * 64 + q * 4);
    a0 += blo(v0.x); a1 += bhi(v0.x);
    a2 += blo(v0.y); a3 += bhi(v0.y);
    a4 += blo(v0.z); a5 += bhi(v0.z);
    a6 += blo(v0.w); a7 += bhi(v0.w);
  }
#pragma unroll
  for (int d = 16; d <= 32; d <<= 1) {
    a0 += __shfl_xor(a0, d); a1 += __shfl_xor(a1, d);
    a2 += __shfl_xor(a2, d); a3 += __shfl_xor(a3, d);
    a4 += __shfl_xor(a4, d); a5 += __shfl_xor(a5, d);
    a6 += __shfl_xor(a6, d); a7 += __shfl_xor(a7, d);
  }
  if (sub == 0) {
    float rd = 1.0f / fmaxf((float)dg, 1.0f);
    uint4 o4;
    o4.x = bf16_2(a0 * rd, a1 * rd);
    o4.y = bf16_2(a2 * rd, a3 * rd);
    o4.z = bf16_2(a4 * rd, a5 * rd);
    o4.w = bf16_2(a6 * rd, a7 * rd);
    *(uint4*)(mean1h + (size_t)node * 64 + q * 4) = o4;
  }
}

// ---------------------------------------------------------------------------
// GEMM1 (MFMA bf16): h = relu([xh | mean1h] @ w1t^T + b1), output bf16.
// One wave per 32 rows, full N=128. No LDS, no syncthreads.
// Fragment layout (m89/m91-verified): A/B lane l: row/col = l&15,
// k = (l>>4)*8 + j (one uint4 = 8 bf16). C/D: col=l&15, row=(l>>4)*4+reg.
// ---------------------------------------------------------------------------
__global__ __launch_bounds__(256) void gemm1_mfma_kernel(
    const uint* __restrict__ xh, const uint* __restrict__ m1h,
    const uint* __restrict__ w1t, const float* __restrict__ b1,
    ushort_t* __restrict__ hout) {
  int wid = (blockIdx.x * 256 + threadIdx.x) >> 6;
  int lane = threadIdx.x & 63;
  int r0 = wid * 32;
  if (r0 >= NN) return;
  int lr = lane & 15, lk = lane >> 4;

  f32x4 acc[2][8];
#pragma unroll
  for (int i = 0; i < 2; i++)
#pragma unroll
    for (int j = 0; j < 8; j++) acc[i][j] = (f32x4){0.f, 0.f, 0.f, 0.f};

#pragma unroll
  for (int ks = 0; ks < 8; ks++) {
    const uint* A = (ks < 4) ? xh : m1h;
    int ku = (ks & 3) * 16;          // uint offset of this k-step in A row
    uint4 a0 = *(const uint4*)(A + (size_t)(r0 + lr) * 64 + ku + lk * 4);
    uint4 a1 = *(const uint4*)(A + (size_t)(r0 + 16 + lr) * 64 + ku + lk * 4);
    int kg = ks * 16;                // uint offset in w1t row (K=256)
#pragma unroll
    for (int ct = 0; ct < 8; ct++) {
      uint4 bu = *(const uint4*)(w1t + (size_t)(ct * 16 + lr) * 128 + kg + lk * 4);
      acc[0][ct] = mfma_bf16(a0, bu, acc[0][ct]);
      acc[1][ct] = mfma_bf16(a1, bu, acc[1][ct]);
    }
  }

#pragma unroll
  for (int rt = 0; rt < 2; rt++) {
#pragma unroll
    for (int r = 0; r < 4; r++) {
      int row = r0 + rt * 16 + lk * 4 + r;
#pragma unroll
      for (int ct = 0; ct < 8; ct++) {
        int col = ct * 16 + lr;
        float v = fmaxf(acc[rt][ct][r] + b1[col], 0.0f);
        hout[(size_t)row * 128 + col] = (ushort_t)bf16_1(v);
      }
    }
  }
}

// ---------------------------------------------------------------------------
// GEMM2 (MFMA bf16): [oself | h2] = h @ w2t^T. K=128, N=32, fp32 out.
// ---------------------------------------------------------------------------
__global__ __launch_bounds__(256) void gemm2_mfma_kernel(
    const uint* __restrict__ h, const uint* __restrict__ w2t,
    float* __restrict__ oself, float* __restrict__ h2) {
  int wid = (blockIdx.x * 256 + threadIdx.x) >> 6;
  int lane = threadIdx.x & 63;
  int r0 = wid * 32;
  if (r0 >= NN) return;
  int lr = lane & 15, lk = lane >> 4;

  f32x4 acc[2][2];
#pragma unroll
  for (int i = 0; i < 2; i++)
#pragma unroll
    for (int j = 0; j < 2; j++) acc[i][j] = (f32x4){0.f, 0.f, 0.f, 0.f};

#pragma unroll
  for (int ks = 0; ks < 4; ks++) {
    int ku = ks * 16;
    uint4 a0 = *(const uint4*)(h + (size_t)(r0 + lr) * 64 + ku + lk * 4);
    uint4 a1 = *(const uint4*)(h + (size_t)(r0 + 16 + lr) * 64 + ku + lk * 4);
#pragma unroll
    for (int ct = 0; ct < 2; ct++) {
      uint4 bu = *(const uint4*)(w2t + (size_t)(ct * 16 + lr) * 64 + ku + lk * 4);
      acc[0][ct] = mfma_bf16(a0, bu, acc[0][ct]);
      acc[1][ct] = mfma_bf16(a1, bu, acc[1][ct]);
    }
  }

#pragma unroll
  for (int rt = 0; rt < 2; rt++) {
#pragma unroll
    for (int r = 0; r < 4; r++) {
      int row = r0 + rt * 16 + lk * 4 + r;
      oself[(size_t)row * 16 + lr] = acc[rt][0][r];
      h2[(size_t)row * 16 + lr]    = acc[rt][1][r];
    }
  }
}

// ---------------------------------------------------------------------------
// Layer-2 mean aggregation: one wave per node, float4/lane, 4 lanes/edge,
// 16 edges in parallel; shfl_xor tree reduce (4..32).
// ---------------------------------------------------------------------------
__global__ __launch_bounds__(256) void mean2_kernel(
    const float* __restrict__ h2, const int* __restrict__ off,
    const int* __restrict__ deg, const int* __restrict__ perm,
    float* __restrict__ mean2) {
  int node = blockIdx.x * 4 + (threadIdx.x >> 6);
  int lane = threadIdx.x & 63;
  if (node >= NN) return;
  int o = off[node], dg = deg[node];
  int sub = lane >> 2;   // 16 edge slots
  int q = lane & 3;      // float4 index within the 16-float row
  float ax = 0.f, ay = 0.f, az = 0.f, aw = 0.f;
  for (int j = sub; j < dg; j += 16) {
    int s = perm[o + j];
    float4 v = *(const float4*)(h2 + (size_t)s * 16 + q * 4);
    ax += v.x; ay += v.y; az += v.z; aw += v.w;
  }
#pragma unroll
  for (int d = 4; d <= 32; d <<= 1) {
    ax += __shfl_xor(ax, d); ay += __shfl_xor(ay, d);
    az += __shfl_xor(az, d); aw += __shfl_xor(aw, d);
  }
  if (sub == 0) {
    float rd = 1.0f / fmaxf((float)dg, 1.0f);
    float4 r; r.x = ax * rd; r.y = ay * rd; r.z = az * rd; r.w = aw * rd;
    *(float4*)(mean2 + (size_t)node * 16 + q * 4) = r;
  }
}

// ---------------------------------------------------------------------------
// Final: logits = oself + b2 + mean2; out = log_softmax(logits).
// ---------------------------------------------------------------------------
__global__ __launch_bounds__(256) void final_kernel(
    const float* __restrict__ oself, const float* __restrict__ mean2,
    const float* __restrict__ b2, float* __restrict__ out) {
  int i = blockIdx.x * 256 + threadIdx.x;
  if (i >= NN) return;
  float l[16];
  const float4* po = (const float4*)(oself + (size_t)i * 16);
  const float4* pa = (const float4*)(mean2 + (size_t)i * 16);
#pragma unroll
  for (int q = 0; q < 4; q++) {
    float4 o = po[q], a = pa[q];
    l[q * 4 + 0] = o.x + b2[q * 4 + 0] + a.x;
    l[q * 4 + 1] = o.y + b2[q * 4 + 1] + a.y;
    l[q * 4 + 2] = o.z + b2[q * 4 + 2] + a.z;
    l[q * 4 + 3] = o.w + b2[q * 4 + 3] + a.w;
  }
  float m = l[0];
#pragma unroll
  for (int c = 1; c < 16; c++) m = fmaxf(m, l[c]);
  float s = 0.0f;
#pragma unroll
  for (int c = 0; c < 16; c++) s += expf(l[c] - m);
  float ls = logf(s);
  float4* po2 = (float4*)(out + (size_t)i * 16);
#pragma unroll
  for (int q = 0; q < 4; q++) {
    float4 v;
    v.x = l[q * 4 + 0] - m - ls;
    v.y = l[q * 4 + 1] - m - ls;
    v.z = l[q * 4 + 2] - m - ls;
    v.w = l[q * 4 + 3] - m - ls;
    po2[q] = v;
  }
}

// ---------------------------------------------------------------------------
extern "C" void kernel_launch(void* const* d_in, const int* in_sizes, int n_in,
                              void* d_out, int out_size, void* d_ws, size_t ws_size,
                              hipStream_t stream) {
  const float* x   = (const float*)d_in[0];
  const int*   src = (const int*)d_in[1];
  const int*   dst = (const int*)d_in[2];
  const float* ws1 = (const float*)d_in[3];
  const float* wn1 = (const float*)d_in[4];
  const float* b1  = (const float*)d_in[5];
  const float* ws2 = (const float*)d_in[6];
  const float* wn2 = (const float*)d_in[7];
  const float* b2  = (const float*)d_in[8];
  float* out = (float*)d_out;

  // workspace layout
  char* p = (char*)d_ws;
  int* deg  = (int*)p;  p += (size_t)NN * 4;
  int* off  = (int*)p;  p += (size_t)NN * 4;
  int* hist = (int*)p;  p += (size_t)NH * 4;             // scanned in place
  int* sums = (int*)p;  p += (size_t)((NSB + 31) & ~31) * 4;
  unsigned int* ebuf = (unsigned int*)p; p += (size_t)NE * 4;
  int* perm = (int*)p;  p += (size_t)NE * 4;
  uint* xh   = (uint*)p; p += (size_t)NN * 64 * 4;       // bf16 x
  uint* m1h  = (uint*)p; p += (size_t)NN * 64 * 4;       // bf16 mean1
  uint* hbuf = (uint*)p; p += (size_t)NN * 64 * 4;       // bf16 h
  uint* w1t  = (uint*)p; p += (size_t)128 * 128 * 4;     // bf16 [ws1;wn1]^T
  uint* w2t  = (uint*)p; p += (size_t)32 * 64 * 4;       // bf16 [ws2|wn2]^T
  float* h2    = (float*)p; p += (size_t)NN * 16 * 4;
  float* osf   = (float*)p; p += (size_t)NN * 16 * 4;
  float* mean2 = (float*)p; p += (size_t)NN * 16 * 4;

  hipMemsetAsync(deg, 0, (size_t)NN * 4, stream);

  tobf16_kernel<<<(NN * 16 + 255) / 256, 256, 0, stream>>>(x, xh);
  prep_w1_kernel<<<(128 * 128 + 255) / 256, 256, 0, stream>>>(ws1, wn1, w1t);
  prep_w2_kernel<<<(32 * 64 + 255) / 256, 256, 0, stream>>>(ws2, wn2, w2t);
  histA_kernel<<<NBLK, 256, 0, stream>>>(dst, deg, hist);
  scan_sums_kernel<<<NSB, 1024, 0, stream>>>(hist, sums);
  scan_tops_kernel<<<1, 512, 0, stream>>>(sums);
  scan_apply_kernel<<<NSB, 1024, 0, stream>>>(hist, sums);
  scatter3_kernel<<<NBLK, 256, 0, stream>>>(src, dst, hist, ebuf);
  bucket_sort_kernel<<<NBUCK, 256, 0, stream>>>(ebuf, hist, deg, off, perm);
  mean1_kernel<<<(NN + 3) / 4, 256, 0, stream>>>(xh, off, deg, perm, m1h);

  int gemm_blocks = (NN + 127) / 128;   // 1 wave = 32 rows, 4 waves/block
  gemm1_mfma_kernel<<<gemm_blocks, 256, 0, stream>>>(
      xh, m1h, w1t, b1, (ushort_t*)hbuf);
  gemm2_mfma_kernel<<<gemm_blocks, 256, 0, stream>>>(hbuf, w2t, osf, h2);

  mean2_kernel<<<(NN + 3) / 4, 256, 0, stream>>>(h2, off, deg, perm, mean2);
  final_kernel<<<(NN + 255) / 256, 256, 0, stream>>>(osf, mean2, b2, out);
}

// Round 10
// 226.908 us; speedup vs baseline: 7.8190x; 1.3080x over previous
//
#include <hip/hip_runtime.h>
#include <math.h>

#define NN 100000
#define NE 1600000
#define BSZ 64                          // dst nodes per bucket
#define NBUCK ((NN + BSZ - 1) / BSZ)    // 1563
#define NBLK 256                        // scatter blocks / hist columns
#define CHUNK ((NE + NBLK - 1) / NBLK)  // 6250 edges per block
#define NH (NBUCK * NBLK)               // 400128 hist entries
#define NSB ((NH + 1023) / 1024)        // 391 scan blocks

typedef unsigned int uint;
typedef unsigned short ushort_t;
typedef float f32x4 __attribute__((ext_vector_type(4)));
typedef short s16x8 __attribute__((ext_vector_type(8)));

union U4S8 { uint4 u; s16x8 s; };

// bf16 helpers (RNE pack, shift-decode)
__device__ inline uint bf16_1(float f) {
  uint u = __float_as_uint(f);
  return (u + 0x7FFFu + ((u >> 16) & 1u)) >> 16;
}
__device__ inline uint bf16_2(float lo, float hi) {
  return bf16_1(lo) | (bf16_1(hi) << 16);
}
__device__ inline float blo(uint u) { return __uint_as_float(u << 16); }
__device__ inline float bhi(uint u) { return __uint_as_float(u & 0xFFFF0000u); }

__device__ inline f32x4 mfma_bf16(uint4 a, uint4 b, f32x4 c) {
  U4S8 ua, ub; ua.u = a; ub.u = b;
  return __builtin_amdgcn_mfma_f32_16x16x32_bf16(ua.s, ub.s, c, 0, 0, 0);
}

// ---------------------------------------------------------------------------
// x (fp32 [NN][128]) -> xh (bf16 pairs, [NN][64] uints). 8 floats/thread.
// ---------------------------------------------------------------------------
__global__ __launch_bounds__(256) void tobf16_kernel(
    const float* __restrict__ x, uint* __restrict__ xh) {
  int i = blockIdx.x * 256 + threadIdx.x;
  if (i >= NN * 16) return;
  const float4* p = (const float4*)x + (size_t)i * 2;
  float4 a = p[0], b = p[1];
  uint4 o;
  o.x = bf16_2(a.x, a.y);
  o.y = bf16_2(a.z, a.w);
  o.z = bf16_2(b.x, b.y);
  o.w = bf16_2(b.z, b.w);
  ((uint4*)xh)[i] = o;
}

// ---------------------------------------------------------------------------
// Weight prep: w1t[col][k] = bf16([ws1;wn1][k][col]), K=256 -> 128 uints/row.
// ---------------------------------------------------------------------------
__global__ __launch_bounds__(256) void prep_w1_kernel(
    const float* __restrict__ ws1, const float* __restrict__ wn1,
    uint* __restrict__ w1t) {
  int idx = blockIdx.x * 256 + threadIdx.x;   // 128 cols * 128 uints
  if (idx >= 128 * 128) return;
  int col = idx >> 7, ku = idx & 127;
  int k = ku * 2;
  const float* w = (k < 128) ? ws1 : wn1;
  int kk = (k < 128) ? k : (k - 128);
  w1t[idx] = bf16_2(w[(size_t)kk * 128 + col], w[(size_t)(kk + 1) * 128 + col]);
}

// w2t[col][k] = bf16([ws2|wn2][k][col]), cols 0..15 = ws2, 16..31 = wn2, K=128.
__global__ __launch_bounds__(256) void prep_w2_kernel(
    const float* __restrict__ ws2, const float* __restrict__ wn2,
    uint* __restrict__ w2t) {
  int idx = blockIdx.x * 256 + threadIdx.x;   // 32 cols * 64 uints
  if (idx >= 32 * 64) return;
  int col = idx >> 6, ku = idx & 63;
  int k = ku * 2;
  const float* w = (col < 16) ? ws2 : wn2;
  int c = col & 15;
  w2t[idx] = bf16_2(w[(size_t)k * 16 + c], w[(size_t)(k + 1) * 16 + c]);
}

// ---------------------------------------------------------------------------
// Pass A: per-block bucket histogram, LDS atomics ONLY (no global atomics),
// coalesced block-major output hist2[b][i]. 1024 threads for latency hiding.
// ---------------------------------------------------------------------------
__global__ __launch_bounds__(1024) void histA_kernel(
    const int* __restrict__ dst, int* __restrict__ hist2) {
  __shared__ int lh[NBUCK];
  int tid = threadIdx.x;
  int b = blockIdx.x;
  for (int i = tid; i < NBUCK; i += 1024) lh[i] = 0;
  __syncthreads();
  int e0 = b * CHUNK, e1 = min(e0 + CHUNK, NE);
  for (int e = e0 + tid; e < e1; e += 1024) {
    atomicAdd(&lh[dst[e] >> 6], 1);
  }
  __syncthreads();
  for (int i = tid; i < NBUCK; i += 1024)
    hist2[(size_t)b * NBUCK + i] = lh[i];
}

// ---------------------------------------------------------------------------
// Transpose hist2[NBLK][NBUCK] -> hist[NBUCK][NBLK] (both sides coalesced).
// ---------------------------------------------------------------------------
__global__ __launch_bounds__(1024) void transpose_kernel(
    const int* __restrict__ hist2, int* __restrict__ hist) {
  __shared__ int t[32][33];
  int tx = threadIdx.x & 31, ty = threadIdx.x >> 5;
  int i = blockIdx.x * 32 + tx;   // bucket idx (read fast dim)
  int b = blockIdx.y * 32 + ty;   // block idx  (always < NBLK=256)
  if (i < NBUCK) t[ty][tx] = hist2[(size_t)b * NBUCK + i];
  __syncthreads();
  int i2 = blockIdx.x * 32 + ty;
  int b2 = blockIdx.y * 32 + tx;
  if (i2 < NBUCK) hist[(size_t)i2 * NBLK + b2] = t[tx][ty];
}

// ---------------------------------------------------------------------------
// Multi-block exclusive scan over hist[NH] (in-place), 3 kernels.
// ---------------------------------------------------------------------------
__global__ __launch_bounds__(1024) void scan_sums_kernel(
    const int* __restrict__ hist, int* __restrict__ sums) {
  __shared__ int sdata[1024];
  int i = blockIdx.x * 1024 + threadIdx.x;
  sdata[threadIdx.x] = (i < NH) ? hist[i] : 0;
  __syncthreads();
#pragma unroll
  for (int s = 512; s > 0; s >>= 1) {
    if (threadIdx.x < s) sdata[threadIdx.x] += sdata[threadIdx.x + s];
    __syncthreads();
  }
  if (threadIdx.x == 0) sums[blockIdx.x] = sdata[0];
}

__global__ __launch_bounds__(512) void scan_tops_kernel(int* __restrict__ sums) {
  __shared__ int buf[2][512];
  int tid = threadIdx.x;
  int v = (tid < NSB) ? sums[tid] : 0;
  buf[0][tid] = v;
  __syncthreads();
  int pp = 0;
#pragma unroll
  for (int d = 1; d < 512; d <<= 1) {
    buf[pp ^ 1][tid] = buf[pp][tid] + ((tid >= d) ? buf[pp][tid - d] : 0);
    pp ^= 1;
    __syncthreads();
  }
  if (tid < NSB) sums[tid] = buf[pp][tid] - v;  // exclusive
}

__global__ __launch_bounds__(1024) void scan_apply_kernel(
    int* __restrict__ hist, const int* __restrict__ sums) {
  __shared__ int buf[2][1024];
  int tid = threadIdx.x;
  int i = blockIdx.x * 1024 + tid;
  int v = (i < NH) ? hist[i] : 0;
  buf[0][tid] = v;
  __syncthreads();
  int pp = 0;
#pragma unroll
  for (int d = 1; d < 1024; d <<= 1) {
    buf[pp ^ 1][tid] = buf[pp][tid] + ((tid >= d) ? buf[pp][tid - d] : 0);
    pp ^= 1;
    __syncthreads();
  }
  if (i < NH) hist[i] = sums[blockIdx.x] + buf[pp][tid] - v;  // exclusive
}

// ---------------------------------------------------------------------------
// Pass C: contention-free scatter via scanned per-(bucket,block) cursors.
// ---------------------------------------------------------------------------
__global__ __launch_bounds__(1024) void scatter3_kernel(
    const int* __restrict__ src, const int* __restrict__ dst,
    const int* __restrict__ scanned, unsigned int* __restrict__ ebuf) {
  __shared__ int cur[NBUCK];
  int tid = threadIdx.x;
  int b = blockIdx.x;
  for (int i = tid; i < NBUCK; i += 1024) cur[i] = scanned[i * NBLK + b];
  __syncthreads();
  int e0 = b * CHUNK, e1 = min(e0 + CHUNK, NE);
  for (int e = e0 + tid; e < e1; e += 1024) {
    int d = dst[e];
    int p = atomicAdd(&cur[d >> 6], 1);
    ebuf[p] = ((unsigned int)(d & 63) << 17) | (unsigned int)src[e];
  }
}

// ---------------------------------------------------------------------------
// Per-bucket counting sort, two-pass: pass 1 LDS-histograms dst-locals
// (computes deg + off, no global atomics anywhere); pass 2 ranks into perm.
// ---------------------------------------------------------------------------
__global__ __launch_bounds__(256) void bucket_sort_kernel(
    const unsigned int* __restrict__ ebuf, const int* __restrict__ scanned,
    int* __restrict__ deg, int* __restrict__ off, int* __restrict__ perm) {
  __shared__ int cnt[BSZ];
  __shared__ int loc_off[BSZ];
  int tid = threadIdx.x;
  int b = blockIdx.x;
  int e0 = scanned[b * NBLK];
  int e1 = (b + 1 < NBUCK) ? scanned[(b + 1) * NBLK] : NE;

  if (tid < BSZ) cnt[tid] = 0;
  __syncthreads();
  for (int e = e0 + tid; e < e1; e += 256)
    atomicAdd(&cnt[ebuf[e] >> 17], 1);
  __syncthreads();

  if (tid < BSZ) {   // threads 0..63 = one wave
    int v = cnt[tid];
    int incl = v;
#pragma unroll
    for (int d = 1; d < 64; d <<= 1) {
      int t = __shfl_up(incl, d);
      if (tid >= d) incl += t;
    }
    int excl = incl - v;
    loc_off[tid] = e0 + excl;
    int node = b * BSZ + tid;
    if (node < NN) { off[node] = e0 + excl; deg[node] = v; }
    cnt[tid] = 0;
  }
  __syncthreads();

  for (int e = e0 + tid; e < e1; e += 256) {
    unsigned int pk = ebuf[e];
    int dl = pk >> 17;
    int p = loc_off[dl] + atomicAdd(&cnt[dl], 1);
    perm[p] = (int)(pk & 0x1FFFF);
  }
}

// ---------------------------------------------------------------------------
// Layer-1 mean aggregation from bf16 rows (256B): one wave per node,
// uint4 (8 bf16) per lane, 16 lanes per row, 4 edges in parallel,
// fp32 accumulate, bf16 output (feeds MFMA GEMM1 directly).
// ---------------------------------------------------------------------------
__global__ __launch_bounds__(256) void mean1_kernel(
    const uint* __restrict__ xh, const int* __restrict__ off,
    const int* __restrict__ deg, const int* __restrict__ perm,
    uint* __restrict__ mean1h) {
  int node = blockIdx.x * 4 + (threadIdx.x >> 6);
  int lane = threadIdx.x & 63;
  if (node >= NN) return;
  int o = off[node], dg = deg[node];
  int sub = lane >> 4;   // 4 edge slots
  int q = lane & 15;     // which uint4 (8 bf16) of the 64-uint row
  float a0 = 0.f, a1 = 0.f, a2 = 0.f, a3 = 0.f;
  float a4 = 0.f, a5 = 0.f, a6 = 0.f, a7 = 0.f;
  int j = sub;
  for (; j + 4 < dg; j += 8) {
    int s0 = perm[o + j];
    int s1 = perm[o + j + 4];
    uint4 v0 = *(const uint4*)(xh + (size_t)s0 * 64 + q * 4);
    uint4 v1 = *(const uint4*)(xh + (size_t)s1 * 64 + q * 4);
    a0 += blo(v0.x) + blo(v1.x); a1 += bhi(v0.x) + bhi(v1.x);
    a2 += blo(v0.y) + blo(v1.y); a3 += bhi(v0.y) + bhi(v1.y);
    a4 += blo(v0.z) + blo(v1.z); a5 += bhi(v0.z) + bhi(v1.z);
    a6 += blo(v0.w) + blo(v1.w); a7 += bhi(v0.w) + bhi(v1.w);
  }
  if (j < dg) {
    int s0 = perm[o + j];
    uint4 v0 = *(const uint4*)(xh + (size_t)s0 * 64 + q * 4);
    a0 += blo(v0.x); a1 += bhi(v0.x);
    a2 += blo(v0.y); a3 += bhi(v0.y);
    a4 += blo(v0.z); a5 += bhi(v0.z);
    a6 += blo(v0.w); a7 += bhi(v0.w);
  }
#pragma unroll
  for (int d = 16; d <= 32; d <<= 1) {
    a0 += __shfl_xor(a0, d); a1 += __shfl_xor(a1, d);
    a2 += __shfl_xor(a2, d); a3 += __shfl_xor(a3, d);
    a4 += __shfl_xor(a4, d); a5 += __shfl_xor(a5, d);
    a6 += __shfl_xor(a6, d); a7 += __shfl_xor(a7, d);
  }
  if (sub == 0) {
    float rd = 1.0f / fmaxf((float)dg, 1.0f);
    uint4 o4;
    o4.x = bf16_2(a0 * rd, a1 * rd);
    o4.y = bf16_2(a2 * rd, a3 * rd);
    o4.z = bf16_2(a4 * rd, a5 * rd);
    o4.w = bf16_2(a6 * rd, a7 * rd);
    *(uint4*)(mean1h + (size_t)node * 64 + q * 4) = o4;
  }
}

// ---------------------------------------------------------------------------
// GEMM1 (MFMA bf16): h = relu([xh | mean1h] @ w1t^T + b1), output bf16.
// One wave per 32 rows, full N=128. No LDS, no syncthreads.
// ---------------------------------------------------------------------------
__global__ __launch_bounds__(256) void gemm1_mfma_kernel(
    const uint* __restrict__ xh, const uint* __restrict__ m1h,
    const uint* __restrict__ w1t, const float* __restrict__ b1,
    ushort_t* __restrict__ hout) {
  int wid = (blockIdx.x * 256 + threadIdx.x) >> 6;
  int lane = threadIdx.x & 63;
  int r0 = wid * 32;
  if (r0 >= NN) return;
  int lr = lane & 15, lk = lane >> 4;

  f32x4 acc[2][8];
#pragma unroll
  for (int i = 0; i < 2; i++)
#pragma unroll
    for (int j = 0; j < 8; j++) acc[i][j] = (f32x4){0.f, 0.f, 0.f, 0.f};

#pragma unroll
  for (int ks = 0; ks < 8; ks++) {
    const uint* A = (ks < 4) ? xh : m1h;
    int ku = (ks & 3) * 16;
    uint4 a0 = *(const uint4*)(A + (size_t)(r0 + lr) * 64 + ku + lk * 4);
    uint4 a1 = *(const uint4*)(A + (size_t)(r0 + 16 + lr) * 64 + ku + lk * 4);
    int kg = ks * 16;
#pragma unroll
    for (int ct = 0; ct < 8; ct++) {
      uint4 bu = *(const uint4*)(w1t + (size_t)(ct * 16 + lr) * 128 + kg + lk * 4);
      acc[0][ct] = mfma_bf16(a0, bu, acc[0][ct]);
      acc[1][ct] = mfma_bf16(a1, bu, acc[1][ct]);
    }
  }

#pragma unroll
  for (int rt = 0; rt < 2; rt++) {
#pragma unroll
    for (int r = 0; r < 4; r++) {
      int row = r0 + rt * 16 + lk * 4 + r;
#pragma unroll
      for (int ct = 0; ct < 8; ct++) {
        int col = ct * 16 + lr;
        float v = fmaxf(acc[rt][ct][r] + b1[col], 0.0f);
        hout[(size_t)row * 128 + col] = (ushort_t)bf16_1(v);
      }
    }
  }
}

// ---------------------------------------------------------------------------
// GEMM2 (MFMA bf16): [oself | h2] = h @ w2t^T. K=128, N=32, fp32 out.
// ---------------------------------------------------------------------------
__global__ __launch_bounds__(256) void gemm2_mfma_kernel(
    const uint* __restrict__ h, const uint* __restrict__ w2t,
    float* __restrict__ oself, float* __restrict__ h2) {
  int wid = (blockIdx.x * 256 + threadIdx.x) >> 6;
  int lane = threadIdx.x & 63;
  int r0 = wid * 32;
  if (r0 >= NN) return;
  int lr = lane & 15, lk = lane >> 4;

  f32x4 acc[2][2];
#pragma unroll
  for (int i = 0; i < 2; i++)
#pragma unroll
    for (int j = 0; j < 2; j++) acc[i][j] = (f32x4){0.f, 0.f, 0.f, 0.f};

#pragma unroll
  for (int ks = 0; ks < 4; ks++) {
    int ku = ks * 16;
    uint4 a0 = *(const uint4*)(h + (size_t)(r0 + lr) * 64 + ku + lk * 4);
    uint4 a1 = *(const uint4*)(h + (size_t)(r0 + 16 + lr) * 64 + ku + lk * 4);
#pragma unroll
    for (int ct = 0; ct < 2; ct++) {
      uint4 bu = *(const uint4*)(w2t + (size_t)(ct * 16 + lr) * 64 + ku + lk * 4);
      acc[0][ct] = mfma_bf16(a0, bu, acc[0][ct]);
      acc[1][ct] = mfma_bf16(a1, bu, acc[1][ct]);
    }
  }

#pragma unroll
  for (int rt = 0; rt < 2; rt++) {
#pragma unroll
    for (int r = 0; r < 4; r++) {
      int row = r0 + rt * 16 + lk * 4 + r;
      oself[(size_t)row * 16 + lr] = acc[rt][0][r];
      h2[(size_t)row * 16 + lr]    = acc[rt][1][r];
    }
  }
}

// ---------------------------------------------------------------------------
// Layer-2 mean aggregation: one wave per node, float4/lane, 4 lanes/edge,
// 16 edges in parallel; shfl_xor tree reduce (4..32).
// ---------------------------------------------------------------------------
__global__ __launch_bounds__(256) void mean2_kernel(
    const float* __restrict__ h2, const int* __restrict__ off,
    const int* __restrict__ deg, const int* __restrict__ perm,
    float* __restrict__ mean2) {
  int node = blockIdx.x * 4 + (threadIdx.x >> 6);
  int lane = threadIdx.x & 63;
  if (node >= NN) return;
  int o = off[node], dg = deg[node];
  int sub = lane >> 2;   // 16 edge slots
  int q = lane & 3;      // float4 index within the 16-float row
  float ax = 0.f, ay = 0.f, az = 0.f, aw = 0.f;
  for (int j = sub; j < dg; j += 16) {
    int s = perm[o + j];
    float4 v = *(const float4*)(h2 + (size_t)s * 16 + q * 4);
    ax += v.x; ay += v.y; az += v.z; aw += v.w;
  }
#pragma unroll
  for (int d = 4; d <= 32; d <<= 1) {
    ax += __shfl_xor(ax, d); ay += __shfl_xor(ay, d);
    az += __shfl_xor(az, d); aw += __shfl_xor(aw, d);
  }
  if (sub == 0) {
    float rd = 1.0f / fmaxf((float)dg, 1.0f);
    float4 r; r.x = ax * rd; r.y = ay * rd; r.z = az * rd; r.w = aw * rd;
    *(float4*)(mean2 + (size_t)node * 16 + q * 4) = r;
  }
}

// ---------------------------------------------------------------------------
// Final: logits = oself + b2 + mean2; out = log_softmax(logits).
// ---------------------------------------------------------------------------
__global__ __launch_bounds__(256) void final_kernel(
    const float* __restrict__ oself, const float* __restrict__ mean2,
    const float* __restrict__ b2, float* __restrict__ out) {
  int i = blockIdx.x * 256 + threadIdx.x;
  if (i >= NN) return;
  float l[16];
  const float4* po = (const float4*)(oself + (size_t)i * 16);
  const float4* pa = (const float4*)(mean2 + (size_t)i * 16);
#pragma unroll
  for (int q = 0; q < 4; q++) {
    float4 o = po[q], a = pa[q];
    l[q * 4 + 0] = o.x + b2[q * 4 + 0] + a.x;
    l[q * 4 + 1] = o.y + b2[q * 4 + 1] + a.y;
    l[q * 4 + 2] = o.z + b2[q * 4 + 2] + a.z;
    l[q * 4 + 3] = o.w + b2[q * 4 + 3] + a.w;
  }
  float m = l[0];
#pragma unroll
  for (int c = 1; c < 16; c++) m = fmaxf(m, l[c]);
  float s = 0.0f;
#pragma unroll
  for (int c = 0; c < 16; c++) s += expf(l[c] - m);
  float ls = logf(s);
  float4* po2 = (float4*)(out + (size_t)i * 16);
#pragma unroll
  for (int q = 0; q < 4; q++) {
    float4 v;
    v.x = l[q * 4 + 0] - m - ls;
    v.y = l[q * 4 + 1] - m - ls;
    v.z = l[q * 4 + 2] - m - ls;
    v.w = l[q * 4 + 3] - m - ls;
    po2[q] = v;
  }
}

// ---------------------------------------------------------------------------
extern "C" void kernel_launch(void* const* d_in, const int* in_sizes, int n_in,
                              void* d_out, int out_size, void* d_ws, size_t ws_size,
                              hipStream_t stream) {
  const float* x   = (const float*)d_in[0];
  const int*   src = (const int*)d_in[1];
  const int*   dst = (const int*)d_in[2];
  const float* ws1 = (const float*)d_in[3];
  const float* wn1 = (const float*)d_in[4];
  const float* b1  = (const float*)d_in[5];
  const float* ws2 = (const float*)d_in[6];
  const float* wn2 = (const float*)d_in[7];
  const float* b2  = (const float*)d_in[8];
  float* out = (float*)d_out;

  // workspace layout
  char* p = (char*)d_ws;
  int* deg   = (int*)p;  p += (size_t)NN * 4;
  int* off   = (int*)p;  p += (size_t)NN * 4;
  int* hist  = (int*)p;  p += (size_t)NH * 4;            // bucket-major, scanned in place
  int* hist2 = (int*)p;  p += (size_t)NH * 4;            // block-major (coalesced write)
  int* sums  = (int*)p;  p += (size_t)((NSB + 31) & ~31) * 4;
  unsigned int* ebuf = (unsigned int*)p; p += (size_t)NE * 4;
  int* perm = (int*)p;  p += (size_t)NE * 4;
  uint* xh   = (uint*)p; p += (size_t)NN * 64 * 4;       // bf16 x
  uint* m1h  = (uint*)p; p += (size_t)NN * 64 * 4;       // bf16 mean1
  uint* hbuf = (uint*)p; p += (size_t)NN * 64 * 4;       // bf16 h
  uint* w1t  = (uint*)p; p += (size_t)128 * 128 * 4;     // bf16 [ws1;wn1]^T
  uint* w2t  = (uint*)p; p += (size_t)32 * 64 * 4;       // bf16 [ws2|wn2]^T
  float* h2    = (float*)p; p += (size_t)NN * 16 * 4;
  float* osf   = (float*)p; p += (size_t)NN * 16 * 4;
  float* mean2 = (float*)p; p += (size_t)NN * 16 * 4;

  tobf16_kernel<<<(NN * 16 + 255) / 256, 256, 0, stream>>>(x, xh);
  prep_w1_kernel<<<(128 * 128 + 255) / 256, 256, 0, stream>>>(ws1, wn1, w1t);
  prep_w2_kernel<<<(32 * 64 + 255) / 256, 256, 0, stream>>>(ws2, wn2, w2t);

  histA_kernel<<<NBLK, 1024, 0, stream>>>(dst, hist2);
  transpose_kernel<<<dim3((NBUCK + 31) / 32, NBLK / 32), 1024, 0, stream>>>(
      hist2, hist);
  scan_sums_kernel<<<NSB, 1024, 0, stream>>>(hist, sums);
  scan_tops_kernel<<<1, 512, 0, stream>>>(sums);
  scan_apply_kernel<<<NSB, 1024, 0, stream>>>(hist, sums);
  scatter3_kernel<<<NBLK, 1024, 0, stream>>>(src, dst, hist, ebuf);
  bucket_sort_kernel<<<NBUCK, 256, 0, stream>>>(ebuf, hist, deg, off, perm);

  mean1_kernel<<<(NN + 3) / 4, 256, 0, stream>>>(xh, off, deg, perm, m1h);

  int gemm_blocks = (NN + 127) / 128;   // 1 wave = 32 rows, 4 waves/block
  gemm1_mfma_kernel<<<gemm_blocks, 256, 0, stream>>>(
      xh, m1h, w1t, b1, (ushort_t*)hbuf);
  gemm2_mfma_kernel<<<gemm_blocks, 256, 0, stream>>>(hbuf, w2t, osf, h2);

  mean2_kernel<<<(NN + 3) / 4, 256, 0, stream>>>(h2, off, deg, perm, mean2);
  final_kernel<<<(NN + 255) / 256, 256, 0, stream>>>(osf, mean2, b2, out);
}

// Round 11
// 186.094 us; speedup vs baseline: 9.5338x; 1.2193x over previous
//
#include <hip/hip_runtime.h>
#include <math.h>

#define NN 100000
#define NE 1600000
#define BSZ 64                          // dst nodes per bucket
#define NBUCK ((NN + BSZ - 1) / BSZ)    // 1563
#define NBLK 256                        // scatter blocks / hist columns
#define CHUNK ((NE + NBLK - 1) / NBLK)  // 6250 edges per block
#define NH (NBUCK * NBLK)               // 400128 hist entries
#define NSB ((NH + 1023) / 1024)        // 391 scan blocks

typedef unsigned int uint;
typedef unsigned short ushort_t;
typedef float f32x4 __attribute__((ext_vector_type(4)));
typedef short s16x8 __attribute__((ext_vector_type(8)));

union U4S8 { uint4 u; s16x8 s; };

// bf16 helpers (RNE pack, shift-decode)
__device__ inline uint bf16_1(float f) {
  uint u = __float_as_uint(f);
  return (u + 0x7FFFu + ((u >> 16) & 1u)) >> 16;
}
__device__ inline uint bf16_2(float lo, float hi) {
  return bf16_1(lo) | (bf16_1(hi) << 16);
}
__device__ inline float blo(uint u) { return __uint_as_float(u << 16); }
__device__ inline float bhi(uint u) { return __uint_as_float(u & 0xFFFF0000u); }

__device__ inline f32x4 mfma_bf16(uint4 a, uint4 b, f32x4 c) {
  U4S8 ua, ub; ua.u = a; ub.u = b;
  return __builtin_amdgcn_mfma_f32_16x16x32_bf16(ua.s, ub.s, c, 0, 0, 0);
}

// ---------------------------------------------------------------------------
// x (fp32 [NN][128]) -> xh (bf16 pairs, [NN][64] uints). 8 floats/thread.
// ---------------------------------------------------------------------------
__global__ __launch_bounds__(256) void tobf16_kernel(
    const float* __restrict__ x, uint* __restrict__ xh) {
  int i = blockIdx.x * 256 + threadIdx.x;
  if (i >= NN * 16) return;
  const float4* p = (const float4*)x + (size_t)i * 2;
  float4 a = p[0], b = p[1];
  uint4 o;
  o.x = bf16_2(a.x, a.y);
  o.y = bf16_2(a.z, a.w);
  o.z = bf16_2(b.x, b.y);
  o.w = bf16_2(b.z, b.w);
  ((uint4*)xh)[i] = o;
}

// ---------------------------------------------------------------------------
// Weight prep: w1t[col][k] = bf16([ws1;wn1][k][col]), K=256 -> 128 uints/row.
// ---------------------------------------------------------------------------
__global__ __launch_bounds__(256) void prep_w1_kernel(
    const float* __restrict__ ws1, const float* __restrict__ wn1,
    uint* __restrict__ w1t) {
  int idx = blockIdx.x * 256 + threadIdx.x;   // 128 cols * 128 uints
  if (idx >= 128 * 128) return;
  int col = idx >> 7, ku = idx & 127;
  int k = ku * 2;
  const float* w = (k < 128) ? ws1 : wn1;
  int kk = (k < 128) ? k : (k - 128);
  w1t[idx] = bf16_2(w[(size_t)kk * 128 + col], w[(size_t)(kk + 1) * 128 + col]);
}

// w2t[col][k] = bf16([ws2|wn2][k][col]), cols 0..15 = ws2, 16..31 = wn2, K=128.
__global__ __launch_bounds__(256) void prep_w2_kernel(
    const float* __restrict__ ws2, const float* __restrict__ wn2,
    uint* __restrict__ w2t) {
  int idx = blockIdx.x * 256 + threadIdx.x;   // 32 cols * 64 uints
  if (idx >= 32 * 64) return;
  int col = idx >> 6, ku = idx & 63;
  int k = ku * 2;
  const float* w = (col < 16) ? ws2 : wn2;
  int c = col & 15;
  w2t[idx] = bf16_2(w[(size_t)k * 16 + c], w[(size_t)(k + 1) * 16 + c]);
}

// ---------------------------------------------------------------------------
// Pass A: per-block bucket histogram, LDS atomics only, coalesced output.
// ---------------------------------------------------------------------------
__global__ __launch_bounds__(1024) void histA_kernel(
    const int* __restrict__ dst, int* __restrict__ hist2) {
  __shared__ int lh[NBUCK];
  int tid = threadIdx.x;
  int b = blockIdx.x;
  for (int i = tid; i < NBUCK; i += 1024) lh[i] = 0;
  __syncthreads();
  int e0 = b * CHUNK, e1 = min(e0 + CHUNK, NE);
  for (int e = e0 + tid; e < e1; e += 1024) {
    atomicAdd(&lh[dst[e] >> 6], 1);
  }
  __syncthreads();
  for (int i = tid; i < NBUCK; i += 1024)
    hist2[(size_t)b * NBUCK + i] = lh[i];
}

// ---------------------------------------------------------------------------
// Transpose hist2[NBLK][NBUCK] -> hist[NBUCK][NBLK].
// ---------------------------------------------------------------------------
__global__ __launch_bounds__(1024) void transpose_kernel(
    const int* __restrict__ hist2, int* __restrict__ hist) {
  __shared__ int t[32][33];
  int tx = threadIdx.x & 31, ty = threadIdx.x >> 5;
  int i = blockIdx.x * 32 + tx;
  int b = blockIdx.y * 32 + ty;
  if (i < NBUCK) t[ty][tx] = hist2[(size_t)b * NBUCK + i];
  __syncthreads();
  int i2 = blockIdx.x * 32 + ty;
  int b2 = blockIdx.y * 32 + tx;
  if (i2 < NBUCK) hist[(size_t)i2 * NBLK + b2] = t[tx][ty];
}

// ---------------------------------------------------------------------------
// Multi-block exclusive scan over hist[NH] (in-place), 3 kernels.
// ---------------------------------------------------------------------------
__global__ __launch_bounds__(1024) void scan_sums_kernel(
    const int* __restrict__ hist, int* __restrict__ sums) {
  __shared__ int sdata[1024];
  int i = blockIdx.x * 1024 + threadIdx.x;
  sdata[threadIdx.x] = (i < NH) ? hist[i] : 0;
  __syncthreads();
#pragma unroll
  for (int s = 512; s > 0; s >>= 1) {
    if (threadIdx.x < s) sdata[threadIdx.x] += sdata[threadIdx.x + s];
    __syncthreads();
  }
  if (threadIdx.x == 0) sums[blockIdx.x] = sdata[0];
}

__global__ __launch_bounds__(512) void scan_tops_kernel(int* __restrict__ sums) {
  __shared__ int buf[2][512];
  int tid = threadIdx.x;
  int v = (tid < NSB) ? sums[tid] : 0;
  buf[0][tid] = v;
  __syncthreads();
  int pp = 0;
#pragma unroll
  for (int d = 1; d < 512; d <<= 1) {
    buf[pp ^ 1][tid] = buf[pp][tid] + ((tid >= d) ? buf[pp][tid - d] : 0);
    pp ^= 1;
    __syncthreads();
  }
  if (tid < NSB) sums[tid] = buf[pp][tid] - v;  // exclusive
}

__global__ __launch_bounds__(1024) void scan_apply_kernel(
    int* __restrict__ hist, const int* __restrict__ sums) {
  __shared__ int buf[2][1024];
  int tid = threadIdx.x;
  int i = blockIdx.x * 1024 + tid;
  int v = (i < NH) ? hist[i] : 0;
  buf[0][tid] = v;
  __syncthreads();
  int pp = 0;
#pragma unroll
  for (int d = 1; d < 1024; d <<= 1) {
    buf[pp ^ 1][tid] = buf[pp][tid] + ((tid >= d) ? buf[pp][tid - d] : 0);
    pp ^= 1;
    __syncthreads();
  }
  if (i < NH) hist[i] = sums[blockIdx.x] + buf[pp][tid] - v;  // exclusive
}

// ---------------------------------------------------------------------------
// Pass C: contention-free scatter via scanned per-(bucket,block) cursors.
// ---------------------------------------------------------------------------
__global__ __launch_bounds__(1024) void scatter3_kernel(
    const int* __restrict__ src, const int* __restrict__ dst,
    const int* __restrict__ scanned, unsigned int* __restrict__ ebuf) {
  __shared__ int cur[NBUCK];
  int tid = threadIdx.x;
  int b = blockIdx.x;
  for (int i = tid; i < NBUCK; i += 1024) cur[i] = scanned[i * NBLK + b];
  __syncthreads();
  int e0 = b * CHUNK, e1 = min(e0 + CHUNK, NE);
  for (int e = e0 + tid; e < e1; e += 1024) {
    int d = dst[e];
    int p = atomicAdd(&cur[d >> 6], 1);
    ebuf[p] = ((unsigned int)(d & 63) << 17) | (unsigned int)src[e];
  }
}

// ---------------------------------------------------------------------------
// Per-bucket counting sort, two-pass (computes deg + off, no global atomics).
// ---------------------------------------------------------------------------
__global__ __launch_bounds__(256) void bucket_sort_kernel(
    const unsigned int* __restrict__ ebuf, const int* __restrict__ scanned,
    int* __restrict__ deg, int* __restrict__ off, int* __restrict__ perm) {
  __shared__ int cnt[BSZ];
  __shared__ int loc_off[BSZ];
  int tid = threadIdx.x;
  int b = blockIdx.x;
  int e0 = scanned[b * NBLK];
  int e1 = (b + 1 < NBUCK) ? scanned[(b + 1) * NBLK] : NE;

  if (tid < BSZ) cnt[tid] = 0;
  __syncthreads();
  for (int e = e0 + tid; e < e1; e += 256)
    atomicAdd(&cnt[ebuf[e] >> 17], 1);
  __syncthreads();

  if (tid < BSZ) {   // threads 0..63 = one wave
    int v = cnt[tid];
    int incl = v;
#pragma unroll
    for (int d = 1; d < 64; d <<= 1) {
      int t = __shfl_up(incl, d);
      if (tid >= d) incl += t;
    }
    int excl = incl - v;
    loc_off[tid] = e0 + excl;
    int node = b * BSZ + tid;
    if (node < NN) { off[node] = e0 + excl; deg[node] = v; }
    cnt[tid] = 0;
  }
  __syncthreads();

  for (int e = e0 + tid; e < e1; e += 256) {
    unsigned int pk = ebuf[e];
    int dl = pk >> 17;
    int p = loc_off[dl] + atomicAdd(&cnt[dl], 1);
    perm[p] = (int)(pk & 0x1FFFF);
  }
}

// ---------------------------------------------------------------------------
// Layer-1 mean aggregation from bf16 rows (256B): one wave per node,
// uint4 (8 bf16) per lane, 16 lanes per row, 4 edges in parallel,
// fp32 accumulate, bf16 output.
// ---------------------------------------------------------------------------
__global__ __launch_bounds__(256) void mean1_kernel(
    const uint* __restrict__ xh, const int* __restrict__ off,
    const int* __restrict__ deg, const int* __restrict__ perm,
    uint* __restrict__ mean1h) {
  int node = blockIdx.x * 4 + (threadIdx.x >> 6);
  int lane = threadIdx.x & 63;
  if (node >= NN) return;
  int o = off[node], dg = deg[node];
  int sub = lane >> 4;   // 4 edge slots
  int q = lane & 15;     // which uint4 (8 bf16) of the 64-uint row
  float a0 = 0.f, a1 = 0.f, a2 = 0.f, a3 = 0.f;
  float a4 = 0.f, a5 = 0.f, a6 = 0.f, a7 = 0.f;
  int j = sub;
  for (; j + 4 < dg; j += 8) {
    int s0 = perm[o + j];
    int s1 = perm[o + j + 4];
    uint4 v0 = *(const uint4*)(xh + (size_t)s0 * 64 + q * 4);
    uint4 v1 = *(const uint4*)(xh + (size_t)s1 * 64 + q * 4);
    a0 += blo(v0.x) + blo(v1.x); a1 += bhi(v0.x) + bhi(v1.x);
    a2 += blo(v0.y) + blo(v1.y); a3 += bhi(v0.y) + bhi(v1.y);
    a4 += blo(v0.z) + blo(v1.z); a5 += bhi(v0.z) + bhi(v1.z);
    a6 += blo(v0.w) + blo(v1.w); a7 += bhi(v0.w) + bhi(v1.w);
  }
  if (j < dg) {
    int s0 = perm[o + j];
    uint4 v0 = *(const uint4*)(xh + (size_t)s0 * 64 + q * 4);
    a0 += blo(v0.x); a1 += bhi(v0.x);
    a2 += blo(v0.y); a3 += bhi(v0.y);
    a4 += blo(v0.z); a5 += bhi(v0.z);
    a6 += blo(v0.w); a7 += bhi(v0.w);
  }
#pragma unroll
  for (int d = 16; d <= 32; d <<= 1) {
    a0 += __shfl_xor(a0, d); a1 += __shfl_xor(a1, d);
    a2 += __shfl_xor(a2, d); a3 += __shfl_xor(a3, d);
    a4 += __shfl_xor(a4, d); a5 += __shfl_xor(a5, d);
    a6 += __shfl_xor(a6, d); a7 += __shfl_xor(a7, d);
  }
  if (sub == 0) {
    float rd = 1.0f / fmaxf((float)dg, 1.0f);
    uint4 o4;
    o4.x = bf16_2(a0 * rd, a1 * rd);
    o4.y = bf16_2(a2 * rd, a3 * rd);
    o4.z = bf16_2(a4 * rd, a5 * rd);
    o4.w = bf16_2(a6 * rd, a7 * rd);
    *(uint4*)(mean1h + (size_t)node * 64 + q * 4) = o4;
  }
}

// ---------------------------------------------------------------------------
// GEMM1 (MFMA bf16, LDS-staged B): h = relu([xh | mean1h] @ w1t^T + b1).
// Block = 256 threads stages w1t (64 KB) into LDS once, XOR-swizzled
// (chunk ^= row&7 -> ds_read_b128 at the wave64 bank floor). Each wave
// computes 64 rows x 128 cols: per k-step 4 A-loads + 8 ds_read B + 32 MFMA.
// ---------------------------------------------------------------------------
__global__ __launch_bounds__(256) void gemm1_mfma_kernel(
    const uint* __restrict__ xh, const uint* __restrict__ m1h,
    const uint* __restrict__ w1t, const float* __restrict__ b1,
    ushort_t* __restrict__ hout) {
  __shared__ uint lds_w[128 * 128];   // 64 KB
  int tid = threadIdx.x;

  // stage w1t: 4096 uint4 chunks, thread t -> chunks t, t+256, ...
#pragma unroll
  for (int i = 0; i < 16; i++) {
    int g = tid + i * 256;
    int row = g >> 5, c = g & 31;
    uint4 v = ((const uint4*)w1t)[g];
    int cs = c ^ (row & 7);
    *(uint4*)&lds_w[row * 128 + cs * 4] = v;
  }
  __syncthreads();

  int wv = tid >> 6;
  int lane = tid & 63;
  int lr = lane & 15, lk = lane >> 4;
  int r0 = blockIdx.x * 256 + wv * 64;
  if (r0 >= NN) return;   // after the only barrier

  f32x4 acc[4][8];
#pragma unroll
  for (int i = 0; i < 4; i++)
#pragma unroll
    for (int j = 0; j < 8; j++) acc[i][j] = (f32x4){0.f, 0.f, 0.f, 0.f};

#pragma unroll
  for (int ks = 0; ks < 8; ks++) {
    const uint* A = (ks < 4) ? xh : m1h;
    int ku = (ks & 3) * 16 + lk * 4;
    uint4 a[4];
#pragma unroll
    for (int rt = 0; rt < 4; rt++) {
      int row = r0 + rt * 16 + lr;
      if (row >= NN) row = NN - 1;
      a[rt] = *(const uint4*)(A + (size_t)row * 64 + ku);
    }
    int cbase = ks * 4 + lk;
#pragma unroll
    for (int ct = 0; ct < 8; ct++) {
      int brow = ct * 16 + lr;
      int cs = cbase ^ (lr & 7);
      uint4 bu = *(const uint4*)&lds_w[brow * 128 + cs * 4];
#pragma unroll
      for (int rt = 0; rt < 4; rt++)
        acc[rt][ct] = mfma_bf16(a[rt], bu, acc[rt][ct]);
    }
  }

  float bias[8];
#pragma unroll
  for (int ct = 0; ct < 8; ct++) bias[ct] = b1[ct * 16 + lr];

#pragma unroll
  for (int rt = 0; rt < 4; rt++) {
#pragma unroll
    for (int r = 0; r < 4; r++) {
      int row = r0 + rt * 16 + lk * 4 + r;
      if (row < NN) {
#pragma unroll
        for (int ct = 0; ct < 8; ct++) {
          int col = ct * 16 + lr;
          float v = fmaxf(acc[rt][ct][r] + bias[ct], 0.0f);
          hout[(size_t)row * 128 + col] = (ushort_t)bf16_1(v);
        }
      }
    }
  }
}

// ---------------------------------------------------------------------------
// GEMM2 (MFMA bf16): [oself | h2] = h @ w2t^T. K=128, N=32, fp32 out.
// ---------------------------------------------------------------------------
__global__ __launch_bounds__(256) void gemm2_mfma_kernel(
    const uint* __restrict__ h, const uint* __restrict__ w2t,
    float* __restrict__ oself, float* __restrict__ h2) {
  int wid = (blockIdx.x * 256 + threadIdx.x) >> 6;
  int lane = threadIdx.x & 63;
  int r0 = wid * 32;
  if (r0 >= NN) return;
  int lr = lane & 15, lk = lane >> 4;

  f32x4 acc[2][2];
#pragma unroll
  for (int i = 0; i < 2; i++)
#pragma unroll
    for (int j = 0; j < 2; j++) acc[i][j] = (f32x4){0.f, 0.f, 0.f, 0.f};

#pragma unroll
  for (int ks = 0; ks < 4; ks++) {
    int ku = ks * 16;
    uint4 a0 = *(const uint4*)(h + (size_t)(r0 + lr) * 64 + ku + lk * 4);
    uint4 a1 = *(const uint4*)(h + (size_t)(r0 + 16 + lr) * 64 + ku + lk * 4);
#pragma unroll
    for (int ct = 0; ct < 2; ct++) {
      uint4 bu = *(const uint4*)(w2t + (size_t)(ct * 16 + lr) * 64 + ku + lk * 4);
      acc[0][ct] = mfma_bf16(a0, bu, acc[0][ct]);
      acc[1][ct] = mfma_bf16(a1, bu, acc[1][ct]);
    }
  }

#pragma unroll
  for (int rt = 0; rt < 2; rt++) {
#pragma unroll
    for (int r = 0; r < 4; r++) {
      int row = r0 + rt * 16 + lk * 4 + r;
      oself[(size_t)row * 16 + lr] = acc[rt][0][r];
      h2[(size_t)row * 16 + lr]    = acc[rt][1][r];
    }
  }
}

// ---------------------------------------------------------------------------
// Layer-2 mean aggregation: one wave per node, float4/lane, 4 lanes/edge,
// 16 edges in parallel; shfl_xor tree reduce (4..32).
// ---------------------------------------------------------------------------
__global__ __launch_bounds__(256) void mean2_kernel(
    const float* __restrict__ h2, const int* __restrict__ off,
    const int* __restrict__ deg, const int* __restrict__ perm,
    float* __restrict__ mean2) {
  int node = blockIdx.x * 4 + (threadIdx.x >> 6);
  int lane = threadIdx.x & 63;
  if (node >= NN) return;
  int o = off[node], dg = deg[node];
  int sub = lane >> 2;   // 16 edge slots
  int q = lane & 3;      // float4 index within the 16-float row
  float ax = 0.f, ay = 0.f, az = 0.f, aw = 0.f;
  for (int j = sub; j < dg; j += 16) {
    int s = perm[o + j];
    float4 v = *(const float4*)(h2 + (size_t)s * 16 + q * 4);
    ax += v.x; ay += v.y; az += v.z; aw += v.w;
  }
#pragma unroll
  for (int d = 4; d <= 32; d <<= 1) {
    ax += __shfl_xor(ax, d); ay += __shfl_xor(ay, d);
    az += __shfl_xor(az, d); aw += __shfl_xor(aw, d);
  }
  if (sub == 0) {
    float rd = 1.0f / fmaxf((float)dg, 1.0f);
    float4 r; r.x = ax * rd; r.y = ay * rd; r.z = az * rd; r.w = aw * rd;
    *(float4*)(mean2 + (size_t)node * 16 + q * 4) = r;
  }
}

// ---------------------------------------------------------------------------
// Final: logits = oself + b2 + mean2; out = log_softmax(logits).
// ---------------------------------------------------------------------------
__global__ __launch_bounds__(256) void final_kernel(
    const float* __restrict__ oself, const float* __restrict__ mean2,
    const float* __restrict__ b2, float* __restrict__ out) {
  int i = blockIdx.x * 256 + threadIdx.x;
  if (i >= NN) return;
  float l[16];
  const float4* po = (const float4*)(oself + (size_t)i * 16);
  const float4* pa = (const float4*)(mean2 + (size_t)i * 16);
#pragma unroll
  for (int q = 0; q < 4; q++) {
    float4 o = po[q], a = pa[q];
    l[q * 4 + 0] = o.x + b2[q * 4 + 0] + a.x;
    l[q * 4 + 1] = o.y + b2[q * 4 + 1] + a.y;
    l[q * 4 + 2] = o.z + b2[q * 4 + 2] + a.z;
    l[q * 4 + 3] = o.w + b2[q * 4 + 3] + a.w;
  }
  float m = l[0];
#pragma unroll
  for (int c = 1; c < 16; c++) m = fmaxf(m, l[c]);
  float s = 0.0f;
#pragma unroll
  for (int c = 0; c < 16; c++) s += expf(l[c] - m);
  float ls = logf(s);
  float4* po2 = (float4*)(out + (size_t)i * 16);
#pragma unroll
  for (int q = 0; q < 4; q++) {
    float4 v;
    v.x = l[q * 4 + 0] - m - ls;
    v.y = l[q * 4 + 1] - m - ls;
    v.z = l[q * 4 + 2] - m - ls;
    v.w = l[q * 4 + 3] - m - ls;
    po2[q] = v;
  }
}

// ---------------------------------------------------------------------------
extern "C" void kernel_launch(void* const* d_in, const int* in_sizes, int n_in,
                              void* d_out, int out_size, void* d_ws, size_t ws_size,
                              hipStream_t stream) {
  const float* x   = (const float*)d_in[0];
  const int*   src = (const int*)d_in[1];
  const int*   dst = (const int*)d_in[2];
  const float* ws1 = (const float*)d_in[3];
  const float* wn1 = (const float*)d_in[4];
  const float* b1  = (const float*)d_in[5];
  const float* ws2 = (const float*)d_in[6];
  const float* wn2 = (const float*)d_in[7];
  const float* b2  = (const float*)d_in[8];
  float* out = (float*)d_out;

  // workspace layout
  char* p = (char*)d_ws;
  int* deg   = (int*)p;  p += (size_t)NN * 4;
  int* off   = (int*)p;  p += (size_t)NN * 4;
  int* hist  = (int*)p;  p += (size_t)NH * 4;            // bucket-major, scanned in place
  int* hist2 = (int*)p;  p += (size_t)NH * 4;            // block-major
  int* sums  = (int*)p;  p += (size_t)((NSB + 31) & ~31) * 4;
  unsigned int* ebuf = (unsigned int*)p; p += (size_t)NE * 4;
  int* perm = (int*)p;  p += (size_t)NE * 4;
  uint* xh   = (uint*)p; p += (size_t)NN * 64 * 4;       // bf16 x
  uint* m1h  = (uint*)p; p += (size_t)NN * 64 * 4;       // bf16 mean1
  uint* hbuf = (uint*)p; p += (size_t)NN * 64 * 4;       // bf16 h
  uint* w1t  = (uint*)p; p += (size_t)128 * 128 * 4;     // bf16 [ws1;wn1]^T
  uint* w2t  = (uint*)p; p += (size_t)32 * 64 * 4;       // bf16 [ws2|wn2]^T
  float* h2    = (float*)p; p += (size_t)NN * 16 * 4;
  float* osf   = (float*)p; p += (size_t)NN * 16 * 4;
  float* mean2 = (float*)p; p += (size_t)NN * 16 * 4;

  tobf16_kernel<<<(NN * 16 + 255) / 256, 256, 0, stream>>>(x, xh);
  prep_w1_kernel<<<(128 * 128 + 255) / 256, 256, 0, stream>>>(ws1, wn1, w1t);
  prep_w2_kernel<<<(32 * 64 + 255) / 256, 256, 0, stream>>>(ws2, wn2, w2t);

  histA_kernel<<<NBLK, 1024, 0, stream>>>(dst, hist2);
  transpose_kernel<<<dim3((NBUCK + 31) / 32, NBLK / 32), 1024, 0, stream>>>(
      hist2, hist);
  scan_sums_kernel<<<NSB, 1024, 0, stream>>>(hist, sums);
  scan_tops_kernel<<<1, 512, 0, stream>>>(sums);
  scan_apply_kernel<<<NSB, 1024, 0, stream>>>(hist, sums);
  scatter3_kernel<<<NBLK, 1024, 0, stream>>>(src, dst, hist, ebuf);
  bucket_sort_kernel<<<NBUCK, 256, 0, stream>>>(ebuf, hist, deg, off, perm);

  mean1_kernel<<<(NN + 3) / 4, 256, 0, stream>>>(xh, off, deg, perm, m1h);

  gemm1_mfma_kernel<<<(NN + 255) / 256, 256, 0, stream>>>(
      xh, m1h, w1t, b1, (ushort_t*)hbuf);
  gemm2_mfma_kernel<<<(NN + 127) / 128, 256, 0, stream>>>(hbuf, w2t, osf, h2);

  mean2_kernel<<<(NN + 3) / 4, 256, 0, stream>>>(h2, off, deg, perm, mean2);
  final_kernel<<<(NN + 255) / 256, 256, 0, stream>>>(osf, mean2, b2, out);
}